// Round 7
// baseline (534.284 us; speedup 1.0000x reference)
//
#include <hip/hip_runtime.h>
#include <hip/hip_bf16.h>

// GCN: 3x (aggregate -> linear) with BN+ReLU between layers.
// R7: agg gather loop made wave-uniform (nfull guard-free iterations + 1
// guarded tail; s/e are per-wave so trip count is scalar) -- R6's divergent
// while-loop was VALU-bound (62% VALUBusy). BN2-apply+ReLU fused into
// gemm3's A-load (bn_apply pass deleted). CSR bucket sort as R5/R6.

using short8 = __attribute__((ext_vector_type(8))) short;
using f32x4  = __attribute__((ext_vector_type(4))) float;

__device__ __forceinline__ float bf_lo(unsigned int u) { return __uint_as_float(u << 16); }
__device__ __forceinline__ float bf_hi(unsigned int u) { return __uint_as_float(u & 0xffff0000u); }
__device__ __forceinline__ unsigned short f2bf(float f) {
    __hip_bfloat16 h = __float2bfloat16(f);
    return *reinterpret_cast<unsigned short*>(&h);
}
__device__ __forceinline__ int clampi(int v, int lo, int hi) {
    return v < lo ? lo : (v > hi ? hi : v);
}

#define BSH 7      // 128 nodes per bucket
#define CHUNK 8192 // edges per scatter block

// ---------------- dtype detection ----------------

__global__ void detect_kernel(const unsigned int* __restrict__ gamma_raw,
                              const int* __restrict__ edge_raw, int* __restrict__ flags) {
    if (blockIdx.x == 0 && threadIdx.x == 0) {
        flags[0] = (gamma_raw[0] == 0x3F803F80u) ? 1 : 0;
        int is64 = 1;
        for (int i = 1; i <= 15; i += 2)
            if (edge_raw[i] != 0) is64 = 0;
        flags[1] = is64;
    }
}

// ---------------- param conversion ----------------

struct CvtPack {
    const void* src[10];
    void* dstA[10];
    void* dstB[10];
    int sz[10];
    int mode[10];
};

__global__ void cvt_params_kernel(CvtPack pp, const int* __restrict__ flags) {
    int b = blockIdx.x;
    int sz = pp.sz[b];
    int bf = flags[0];
    for (int i = threadIdx.x; i < sz; i += blockDim.x) {
        float w = bf ? __bfloat162float(((const __hip_bfloat16*)pp.src[b])[i])
                     : ((const float*)pp.src[b])[i];
        if (pp.mode[b] == 0) {
            ((float*)pp.dstA[b])[i] = w;
        } else {
            __hip_bfloat16 hi = __float2bfloat16(w);
            float r = w - __bfloat162float(hi);
            ((__hip_bfloat16*)pp.dstA[b])[i] = hi;
            ((__hip_bfloat16*)pp.dstB[b])[i] = __float2bfloat16(r);
        }
    }
}

// ---------------- CSR build: bucket sort ----------------

__global__ __launch_bounds__(256) void bucket_count_kernel(
    const int* __restrict__ edge, const int* __restrict__ flags,
    int* __restrict__ bucket_cnt, int E, int n, int NB) {
    __shared__ int hist[1024];
    for (int i = threadIdx.x; i < NB; i += 256) hist[i] = 0;
    __syncthreads();
    int base = blockIdx.x * CHUNK;
    int end = base + CHUNK < E ? base + CHUNK : E;
    int is64 = flags[1];
    for (int e = base + (int)threadIdx.x; e < end; e += 256) {
        int r = is64 ? edge[2 * e] : edge[e];
        r = clampi(r, 0, n - 1);
        atomicAdd(&hist[r >> BSH], 1);
    }
    __syncthreads();
    for (int i = threadIdx.x; i < NB; i += 256) {
        int v = hist[i];
        if (v) atomicAdd(&bucket_cnt[i], v);
    }
}

__global__ __launch_bounds__(1024) void bucket_scan_kernel(
    const int* __restrict__ bucket_cnt, int* __restrict__ bucket_base,
    int* __restrict__ bucket_cursor, int* __restrict__ row_ptr, int NB, int n, int E) {
    __shared__ int sh[1024];
    int t = threadIdx.x;
    int v = (t < NB) ? bucket_cnt[t] : 0;
    sh[t] = v;
    __syncthreads();
    for (int off = 1; off < 1024; off <<= 1) {
        int u = (t >= off) ? sh[t - off] : 0;
        __syncthreads();
        sh[t] += u;
        __syncthreads();
    }
    if (t < NB) {
        int base = sh[t] - v;  // exclusive
        bucket_base[t] = base;
        bucket_cursor[t] = base;
    }
    if (t == 0) row_ptr[n] = E;
}

__global__ __launch_bounds__(256) void bucket_scatter_kernel(
    const int* __restrict__ edge, const int* __restrict__ flags,
    int* __restrict__ bucket_cursor, unsigned* __restrict__ packed,
    int E, int n, int NB) {
    __shared__ int hist[1024];
    __shared__ int cur[1024];
    int t = threadIdx.x;
    for (int i = t; i < NB; i += 256) hist[i] = 0;
    __syncthreads();
    int base = blockIdx.x * CHUNK;
    int end = base + CHUNK < E ? base + CHUNK : E;
    int is64 = flags[1];
    for (int e = base + t; e < end; e += 256) {
        int r = is64 ? edge[2 * e] : edge[e];
        r = clampi(r, 0, n - 1);
        atomicAdd(&hist[r >> BSH], 1);
    }
    __syncthreads();
    for (int i = t; i < NB; i += 256) {
        int h = hist[i];
        cur[i] = h ? atomicAdd(&bucket_cursor[i], h) : 0;
    }
    __syncthreads();
    for (int e = base + t; e < end; e += 256) {
        int r = is64 ? edge[2 * e] : edge[e];
        int c = is64 ? edge[2 * (E + e)] : edge[E + e];
        r = clampi(r, 0, n - 1);
        c = clampi(c, 0, n - 1);
        int p = atomicAdd(&cur[r >> BSH], 1);
        packed[p] = ((unsigned)(r & 127) << 17) | (unsigned)c;  // col < 2^17
    }
}

#define SORT_CAP 4096
__global__ __launch_bounds__(256) void bucket_sort_kernel(
    const unsigned* __restrict__ packed, const int* __restrict__ bucket_base,
    const int* __restrict__ bucket_cnt, int* __restrict__ row_ptr,
    int* __restrict__ col_sorted, int n) {
    __shared__ int hist[128], cur[128];
    __shared__ int out[SORT_CAP];
    int b = blockIdx.x;
    int s = bucket_base[b];
    int cnt = bucket_cnt[b];
    int t = threadIdx.x;
    if (t < 128) hist[t] = 0;
    __syncthreads();
    for (int i = t; i < cnt; i += 256) atomicAdd(&hist[packed[s + i] >> 17], 1);
    __syncthreads();
    int orig = (t < 128) ? hist[t] : 0;
    for (int off = 1; off < 128; off <<= 1) {
        int u = (t < 128 && t >= off) ? hist[t - off] : 0;
        __syncthreads();
        if (t < 128) hist[t] += u;
        __syncthreads();
    }
    if (t < 128) {
        int ex = hist[t] - orig;  // exclusive
        cur[t] = ex;
        int node = (b << BSH) + t;
        if (node < n) row_ptr[node] = s + ex;
    }
    __syncthreads();
    if (cnt <= SORT_CAP) {
        for (int i = t; i < cnt; i += 256) {
            unsigned pk = packed[s + i];
            int p = atomicAdd(&cur[pk >> 17], 1);
            out[p] = (int)(pk & 0x1FFFFu);
        }
        __syncthreads();
        for (int i = t; i < cnt; i += 256) col_sorted[s + i] = out[i];
    } else {  // overflow fallback
        for (int i = t; i < cnt; i += 256) {
            unsigned pk = packed[s + i];
            int p = atomicAdd(&cur[pk >> 17], 1);
            col_sorted[s + p] = (int)(pk & 0x1FFFFu);
        }
    }
}

// ---------------- Aggregation core ----------------
// One node per wave; s,e wave-uniform -> nfull guard-free iterations
// (k = s + sub + it*EPW provably < e) + one guarded tail iteration.

template <typename SRCT>
__device__ __forceinline__ void load8(const SRCT* p, float* v);

template <>
__device__ __forceinline__ void load8<__hip_bfloat16>(const __hip_bfloat16* p, float* v) {
    uint4 u = *reinterpret_cast<const uint4*>(p);
    v[0] = bf_lo(u.x); v[1] = bf_hi(u.x);
    v[2] = bf_lo(u.y); v[3] = bf_hi(u.y);
    v[4] = bf_lo(u.z); v[5] = bf_hi(u.z);
    v[6] = bf_lo(u.w); v[7] = bf_hi(u.w);
}

template <>
__device__ __forceinline__ void load8<float>(const float* p, float* v) {
    float4 a = *reinterpret_cast<const float4*>(p);
    float4 b = *reinterpret_cast<const float4*>(p + 4);
    v[0] = a.x; v[1] = a.y; v[2] = a.z; v[3] = a.w;
    v[4] = b.x; v[5] = b.y; v[6] = b.z; v[7] = b.w;
}

template <typename SRCT, int D, bool APPLY_BN>
__device__ __forceinline__ void agg_gather(const SRCT* __restrict__ src,
                                           const int* __restrict__ cols,
                                           int s, int e, int sub, int c0,
                                           const float* sc, const float* sh,
                                           float* acc) {
    constexpr int LPR = D / 8;
    constexpr int EPW = 64 / LPR;
    int cnt = e - s;
    int nfull = cnt / EPW;          // wave-uniform trip count
    int rem = cnt - nfull * EPW;
    const SRCT* base = src + c0;

    if (nfull > 0) {
        int k = s + sub;
        float v[8];
        load8(base + (size_t)cols[k] * D, v);
        for (int it = 1; it < nfull; ++it) {
            k += EPW;
            float vn[8];
            load8(base + (size_t)cols[k] * D, vn);
#pragma unroll
            for (int j = 0; j < 8; ++j) {
                float t = APPLY_BN ? fmaxf(fmaf(v[j], sc[j], sh[j]), 0.f) : v[j];
                acc[j] += t;
            }
#pragma unroll
            for (int j = 0; j < 8; ++j) v[j] = vn[j];
        }
#pragma unroll
        for (int j = 0; j < 8; ++j) {
            float t = APPLY_BN ? fmaxf(fmaf(v[j], sc[j], sh[j]), 0.f) : v[j];
            acc[j] += t;
        }
    }
    if (sub < rem) {  // single guarded tail iteration
        float v[8];
        load8(base + (size_t)cols[s + nfull * EPW + sub] * D, v);
#pragma unroll
        for (int j = 0; j < 8; ++j) {
            float t = APPLY_BN ? fmaxf(fmaf(v[j], sc[j], sh[j]), 0.f) : v[j];
            acc[j] += t;
        }
    }
}

template <int D, bool APPLY_BN, bool ADD_BIAS, bool OUT_FLAGDT>
__global__ __launch_bounds__(256) void agg_vec_kernel(
    const __hip_bfloat16* __restrict__ src, const int* __restrict__ row_ptr,
    const int* __restrict__ col_sorted, const float* __restrict__ bn_ss,
    const float* __restrict__ bias, void* __restrict__ outp,
    const int* __restrict__ flags, int n) {
    constexpr int LPR = D / 8;
    int lane = threadIdx.x & 63;
    int node = blockIdx.x * 4 + (threadIdx.x >> 6);
    if (node >= n) return;
    int sub = lane / LPR;
    int c0 = (lane % LPR) * 8;

    float sc[8], sh[8];
    if (APPLY_BN) {
#pragma unroll
        for (int j = 0; j < 8; ++j) {
            sc[j] = bn_ss[c0 + j];
            sh[j] = bn_ss[128 + c0 + j];
        }
    }

    int s = row_ptr[node];
    int e = row_ptr[node + 1];
    float acc[8];
#pragma unroll
    for (int j = 0; j < 8; ++j) acc[j] = 0.f;

    agg_gather<__hip_bfloat16, D, APPLY_BN>(src, col_sorted, s, e, sub, c0, sc, sh, acc);

#pragma unroll
    for (int j = 0; j < 8; ++j)
#pragma unroll
        for (int off = LPR; off < 64; off <<= 1) acc[j] += __shfl_xor(acc[j], off, 64);

    if (lane < LPR) {
        float recip = 1.0f / ((float)(e - s) + 1e-6f);
        float m[8];
#pragma unroll
        for (int j = 0; j < 8; ++j) {
            m[j] = acc[j] * recip;
            if (ADD_BIAS) m[j] += bias[c0 + j];
        }
        bool as_bf = !OUT_FLAGDT || flags[0];
        if (as_bf) {
            uint4 o;
            o.x = ((unsigned)f2bf(m[1]) << 16) | f2bf(m[0]);
            o.y = ((unsigned)f2bf(m[3]) << 16) | f2bf(m[2]);
            o.z = ((unsigned)f2bf(m[5]) << 16) | f2bf(m[4]);
            o.w = ((unsigned)f2bf(m[7]) << 16) | f2bf(m[6]);
            *reinterpret_cast<uint4*>((__hip_bfloat16*)outp + (size_t)node * D + c0) = o;
        } else {
            float* op = (float*)outp + (size_t)node * D + c0;
            *reinterpret_cast<float4*>(op) = make_float4(m[0], m[1], m[2], m[3]);
            *reinterpret_cast<float4*>(op + 4) = make_float4(m[4], m[5], m[6], m[7]);
        }
    }
}

// Layer-1 agg over raw x (dtype per flags), D=64, out bf16.
__global__ __launch_bounds__(256) void agg_x_kernel(
    const void* __restrict__ xsrc, const int* __restrict__ flags,
    const int* __restrict__ row_ptr, const int* __restrict__ col_sorted,
    __hip_bfloat16* __restrict__ out, int n) {
    constexpr int D = 64, LPR = 8;
    int lane = threadIdx.x & 63;
    int node = blockIdx.x * 4 + (threadIdx.x >> 6);
    if (node >= n) return;
    int sub = lane / LPR;
    int c0 = (lane % LPR) * 8;
    int s = row_ptr[node];
    int e = row_ptr[node + 1];
    float acc[8];
#pragma unroll
    for (int j = 0; j < 8; ++j) acc[j] = 0.f;

    if (flags[0])
        agg_gather<__hip_bfloat16, D, false>((const __hip_bfloat16*)xsrc, col_sorted,
                                             s, e, sub, c0, nullptr, nullptr, acc);
    else
        agg_gather<float, D, false>((const float*)xsrc, col_sorted,
                                    s, e, sub, c0, nullptr, nullptr, acc);

#pragma unroll
    for (int j = 0; j < 8; ++j)
#pragma unroll
        for (int off = LPR; off < 64; off <<= 1) acc[j] += __shfl_xor(acc[j], off, 64);

    if (lane < LPR) {
        float recip = 1.0f / ((float)(e - s) + 1e-6f);
        float m[8];
#pragma unroll
        for (int j = 0; j < 8; ++j) m[j] = acc[j] * recip;
        uint4 o;
        o.x = ((unsigned)f2bf(m[1]) << 16) | f2bf(m[0]);
        o.y = ((unsigned)f2bf(m[3]) << 16) | f2bf(m[2]);
        o.z = ((unsigned)f2bf(m[5]) << 16) | f2bf(m[4]);
        o.w = ((unsigned)f2bf(m[7]) << 16) | f2bf(m[6]);
        *reinterpret_cast<uint4*>(out + (size_t)node * D + c0) = o;
    }
}

// ---------------- MFMA GEMM, LDS-staged W ----------------
// 256 thr = 4 waves, 128 rows/block. W (hi+lo) staged in fragment order.
// APPLY_BN_A: A-load applies relu(a*scale+shift) per channel (fused BN).

template <int D, int F, bool BIAS, bool APPLY_BN_A>
__global__ __launch_bounds__(256) void gemm_mfma_kernel(
    const __hip_bfloat16* __restrict__ A, const __hip_bfloat16* __restrict__ Whi,
    const __hip_bfloat16* __restrict__ Wlo, const float* __restrict__ bias,
    const float* __restrict__ bn_ss, __hip_bfloat16* __restrict__ C, int n) {
    constexpr int JT = F / 16;
    constexpr int KCH = D / 32;
    constexpr int NF = KCH * JT * 2;
    __shared__ uint4 wlds[NF * 64];  // max 64 KB (D=128,F=128)

    int t = threadIdx.x;
    for (int idx = t; idx < NF * 64; idx += 256) {
        int f = idx >> 6, ln = idx & 63;
        int kc = f / (JT * 2);
        int rem = f % (JT * 2);
        int jt = rem >> 1, h = rem & 1;
        int mm = ln & 15, qq = ln >> 4;
        const __hip_bfloat16* src =
            (h ? Wlo : Whi) + (size_t)(jt * 16 + mm) * D + kc * 32 + qq * 8;
        wlds[idx] = *reinterpret_cast<const uint4*>(src);
    }

    int lane = t & 63;
    int wave = t >> 6;
    int m = lane & 15;
    int quad = lane >> 4;
    int row_base = blockIdx.x * 128 + wave * 32;

    short8 af[2][KCH];
#pragma unroll
    for (int rs = 0; rs < 2; ++rs) {
        int r = row_base + rs * 16 + m;
        r = r < n ? r : n - 1;
        const __hip_bfloat16* ap = A + (size_t)r * D + quad * 8;
#pragma unroll
        for (int kc = 0; kc < KCH; ++kc) {
            union { uint4 u; short8 s; } tmp;
            tmp.u = *reinterpret_cast<const uint4*>(ap + kc * 32);
            af[rs][kc] = tmp.s;
        }
    }
    if (APPLY_BN_A) {
#pragma unroll
        for (int kc = 0; kc < KCH; ++kc) {
            int ch0 = kc * 32 + quad * 8;
            float sc[8], sh[8];
            *reinterpret_cast<float4*>(sc) = *reinterpret_cast<const float4*>(bn_ss + ch0);
            *reinterpret_cast<float4*>(sc + 4) = *reinterpret_cast<const float4*>(bn_ss + ch0 + 4);
            *reinterpret_cast<float4*>(sh) = *reinterpret_cast<const float4*>(bn_ss + 128 + ch0);
            *reinterpret_cast<float4*>(sh + 4) = *reinterpret_cast<const float4*>(bn_ss + 128 + ch0 + 4);
#pragma unroll
            for (int rs = 0; rs < 2; ++rs) {
#pragma unroll
                for (int j = 0; j < 8; ++j) {
                    float v = __uint_as_float(
                        ((unsigned)(unsigned short)af[rs][kc][j]) << 16);
                    v = fmaxf(fmaf(v, sc[j], sh[j]), 0.f);
                    af[rs][kc][j] = (short)f2bf(v);
                }
            }
        }
    }

    f32x4 acc[2][JT];
#pragma unroll
    for (int rs = 0; rs < 2; ++rs)
#pragma unroll
        for (int j = 0; j < JT; ++j) acc[rs][j] = {0.f, 0.f, 0.f, 0.f};

    __syncthreads();

#pragma unroll
    for (int kc = 0; kc < KCH; ++kc) {
#pragma unroll
        for (int jt = 0; jt < JT; ++jt) {
            int fb = (kc * JT + jt) * 2;
            union { uint4 u; short8 s; } bh, bl;
            bh.u = wlds[fb * 64 + lane];
            bl.u = wlds[(fb + 1) * 64 + lane];
            acc[0][jt] = __builtin_amdgcn_mfma_f32_16x16x32_bf16(af[0][kc], bh.s, acc[0][jt], 0, 0, 0);
            acc[1][jt] = __builtin_amdgcn_mfma_f32_16x16x32_bf16(af[1][kc], bh.s, acc[1][jt], 0, 0, 0);
            acc[0][jt] = __builtin_amdgcn_mfma_f32_16x16x32_bf16(af[0][kc], bl.s, acc[0][jt], 0, 0, 0);
            acc[1][jt] = __builtin_amdgcn_mfma_f32_16x16x32_bf16(af[1][kc], bl.s, acc[1][jt], 0, 0, 0);
        }
    }

#pragma unroll
    for (int rs = 0; rs < 2; ++rs) {
#pragma unroll
        for (int jt = 0; jt < JT; ++jt) {
            int col = jt * 16 + m;
            float bv = BIAS ? bias[col] : 0.f;
#pragma unroll
            for (int i = 0; i < 4; ++i) {
                int row = row_base + rs * 16 + quad * 4 + i;
                if (row < n)
                    C[(size_t)row * F + col] = __float2bfloat16(acc[rs][jt][i] + bv);
            }
        }
    }
}

// ---------------- BatchNorm ----------------

__global__ __launch_bounds__(256) void bn_stats_kernel(const __hip_bfloat16* __restrict__ X,
                                                       int n, float* __restrict__ sums) {
    __shared__ float red[2][16][128];
    int g = threadIdx.x & 15;
    int r0 = threadIdx.x >> 4;
    float s[8], q[8];
#pragma unroll
    for (int j = 0; j < 8; ++j) s[j] = q[j] = 0.f;
    for (int i = blockIdx.x * 16 + r0; i < n; i += gridDim.x * 16) {
        uint4 u = *reinterpret_cast<const uint4*>(X + (size_t)i * 128 + g * 8);
        float v[8];
        v[0] = bf_lo(u.x); v[1] = bf_hi(u.x);
        v[2] = bf_lo(u.y); v[3] = bf_hi(u.y);
        v[4] = bf_lo(u.z); v[5] = bf_hi(u.z);
        v[6] = bf_lo(u.w); v[7] = bf_hi(u.w);
#pragma unroll
        for (int j = 0; j < 8; ++j) {
            s[j] += v[j];
            q[j] += v[j] * v[j];
        }
    }
#pragma unroll
    for (int j = 0; j < 8; ++j) {
        red[0][r0][g * 8 + j] = s[j];
        red[1][r0][g * 8 + j] = q[j];
    }
    __syncthreads();
    for (int step = 8; step >= 1; step >>= 1) {
        if (r0 < step) {
#pragma unroll
            for (int j = 0; j < 8; ++j) {
                red[0][r0][g * 8 + j] += red[0][r0 + step][g * 8 + j];
                red[1][r0][g * 8 + j] += red[1][r0 + step][g * 8 + j];
            }
        }
        __syncthreads();
    }
    if (r0 == 0) {
#pragma unroll
        for (int j = 0; j < 8; ++j) {
            atomicAdd(&sums[g * 8 + j], red[0][0][g * 8 + j]);
            atomicAdd(&sums[128 + g * 8 + j], red[1][0][g * 8 + j]);
        }
    }
}

__global__ void bn_finalize_kernel(const float* __restrict__ sums,
                                   const float* __restrict__ gamma,
                                   const float* __restrict__ beta,
                                   float* __restrict__ ss, int n) {
    int c = threadIdx.x;  // 128
    float inv_n = 1.0f / (float)n;
    float mean = sums[c] * inv_n;
    float var = sums[128 + c] * inv_n - mean * mean;
    float inv = rsqrtf(var + 1e-5f);
    float scale = gamma[c] * inv;
    ss[c] = scale;
    ss[128 + c] = beta[c] - mean * scale;
}

// ---------------- launch ----------------

extern "C" void kernel_launch(void* const* d_in, const int* in_sizes, int n_in,
                              void* d_out, int out_size, void* d_ws, size_t ws_size,
                              hipStream_t stream) {
    const void* x   = d_in[0];
    const int* edge = (const int*)d_in[1];

    int n = in_sizes[0] / 64;   // 100000
    int E = in_sizes[1] / 2;    // 1600000
    int NB = (n + 127) >> BSH;  // 782

    char* p = (char*)d_ws;
    auto carve = [&](size_t bytes) {
        char* q = p;
        p += (bytes + 255) & ~(size_t)255;
        return q;
    };
    int* flags      = (int*)carve(64);
    float* params   = (float*)carve(1024 * 4);
    __hip_bfloat16* Whi1 = (__hip_bfloat16*)carve(8192 * 2);
    __hip_bfloat16* Wlo1 = (__hip_bfloat16*)carve(8192 * 2);
    __hip_bfloat16* Whi2 = (__hip_bfloat16*)carve(16384 * 2);
    __hip_bfloat16* Wlo2 = (__hip_bfloat16*)carve(16384 * 2);
    __hip_bfloat16* Whi3 = (__hip_bfloat16*)carve(8192 * 2);
    __hip_bfloat16* Wlo3 = (__hip_bfloat16*)carve(8192 * 2);
    int* row_ptr    = (int*)carve((size_t)(n + 1) * 4);
    int* bucket_cnt = (int*)carve(1024 * 4);
    int* bucket_base= (int*)carve(1024 * 4);
    int* bucket_cur = (int*)carve(1024 * 4);
    float* bn_sums  = (float*)carve(256 * 4);
    float* bn_ss1   = (float*)carve(256 * 4);
    float* bn_ss2   = (float*)carve(256 * 4);
    unsigned* packed= (unsigned*)carve((size_t)E * 4);
    int* col_sorted = (int*)carve((size_t)E * 4);
    __hip_bfloat16* bufA = (__hip_bfloat16*)carve((size_t)n * 128 * 2);
    __hip_bfloat16* bufB = (__hip_bfloat16*)carve((size_t)n * 128 * 2);
    carve(65536);  // slack

    float* b1f = params;        // 128
    float* g1f = b1f + 128;     // 128
    float* be1f = g1f + 128;    // 128
    float* b2f = be1f + 128;    // 128
    float* g2f = b2f + 128;     // 128
    float* be2f = g2f + 128;    // 128
    float* b3f = be2f + 128;    // 64

    detect_kernel<<<1, 1, 0, stream>>>((const unsigned int*)d_in[4], edge, flags);

    CvtPack pp;
    const int pidx[10] = {2, 3, 4, 5, 6, 7, 8, 9, 10, 11};
    void* pa[10] = {Whi1, b1f, g1f, be1f, Whi2, b2f, g2f, be2f, Whi3, b3f};
    void* pb[10] = {Wlo1, nullptr, nullptr, nullptr, Wlo2, nullptr, nullptr, nullptr, Wlo3, nullptr};
    const int psz[10] = {8192, 128, 128, 128, 16384, 128, 128, 128, 8192, 64};
    const int pmode[10] = {1, 0, 0, 0, 1, 0, 0, 0, 1, 0};
    for (int i = 0; i < 10; ++i) {
        pp.src[i] = d_in[pidx[i]];
        pp.dstA[i] = pa[i];
        pp.dstB[i] = pb[i];
        pp.sz[i] = psz[i];
        pp.mode[i] = pmode[i];
    }
    cvt_params_kernel<<<10, 256, 0, stream>>>(pp, flags);

    // CSR build via bucket sort (block-reservation scatter)
    hipMemsetAsync(bucket_cnt, 0, 1024 * 4, stream);
    int nchunks = (E + CHUNK - 1) / CHUNK;
    bucket_count_kernel<<<nchunks, 256, 0, stream>>>(edge, flags, bucket_cnt, E, n, NB);
    bucket_scan_kernel<<<1, 1024, 0, stream>>>(bucket_cnt, bucket_base, bucket_cur, row_ptr, NB, n, E);
    bucket_scatter_kernel<<<nchunks, 256, 0, stream>>>(edge, flags, bucket_cur, packed, E, n, NB);
    bucket_sort_kernel<<<NB, 256, 0, stream>>>(packed, bucket_base, bucket_cnt, row_ptr, col_sorted, n);

    int gemm_grid = (n + 127) / 128;
    int agg_grid = (n + 3) / 4;

    // Layer 1: agg(x) D=64 -> bufA ; MFMA gemm -> bufB ; BN1 stats
    agg_x_kernel<<<agg_grid, 256, 0, stream>>>(x, flags, row_ptr, col_sorted, bufA, n);
    gemm_mfma_kernel<64, 128, true, false><<<gemm_grid, 256, 0, stream>>>(
        bufA, Whi1, Wlo1, b1f, nullptr, bufB, n);
    hipMemsetAsync(bn_sums, 0, 256 * 4, stream);
    bn_stats_kernel<<<256, 256, 0, stream>>>(bufB, n, bn_sums);
    bn_finalize_kernel<<<1, 128, 0, stream>>>(bn_sums, g1f, be1f, bn_ss1, n);

    // Layer 2: agg with fused BN1+ReLU -> bufA ; gemm -> bufB ; BN2 stats
    agg_vec_kernel<128, true, false, false><<<agg_grid, 256, 0, stream>>>(
        bufB, row_ptr, col_sorted, bn_ss1, nullptr, bufA, flags, n);
    gemm_mfma_kernel<128, 128, true, false><<<gemm_grid, 256, 0, stream>>>(
        bufA, Whi2, Wlo2, b2f, nullptr, bufB, n);
    hipMemsetAsync(bn_sums, 0, 256 * 4, stream);
    bn_stats_kernel<<<256, 256, 0, stream>>>(bufB, n, bn_sums);
    bn_finalize_kernel<<<1, 128, 0, stream>>>(bn_sums, g2f, be2f, bn_ss2, n);

    // Layer 3 (reordered): gemm with fused BN2+ReLU on A (no bias) -> bufA[N x 64];
    // agg D=64 + bias -> d_out
    gemm_mfma_kernel<128, 64, false, true><<<gemm_grid, 256, 0, stream>>>(
        bufB, Whi3, Wlo3, nullptr, bn_ss2, bufA, n);
    agg_vec_kernel<64, false, true, true><<<agg_grid, 256, 0, stream>>>(
        bufA, row_ptr, col_sorted, nullptr, b3f, d_out, flags, n);
}

// Round 8
// 530.025 us; speedup vs baseline: 1.0080x; 1.0080x over previous
//
#include <hip/hip_runtime.h>
#include <hip/hip_bf16.h>

// GCN: 3x (aggregate -> linear) with BN+ReLU between layers.
// R8: agg gather loop is a PURE SUM (BN1 hoisted back into a once-per-row
// bn_apply pass -- R7 fused it into the gather, paying deg~16x redundant
// VALU in the hot loop). uint4 prefetch (4-reg copy), wave-uniform trips.
// gemm3 keeps fused BN2-on-A (once per row). CSR bucket sort as R5-R7.

using short8 = __attribute__((ext_vector_type(8))) short;
using f32x4  = __attribute__((ext_vector_type(4))) float;

__device__ __forceinline__ float bf_lo(unsigned int u) { return __uint_as_float(u << 16); }
__device__ __forceinline__ float bf_hi(unsigned int u) { return __uint_as_float(u & 0xffff0000u); }
__device__ __forceinline__ unsigned short f2bf(float f) {
    __hip_bfloat16 h = __float2bfloat16(f);
    return *reinterpret_cast<unsigned short*>(&h);
}
__device__ __forceinline__ int clampi(int v, int lo, int hi) {
    return v < lo ? lo : (v > hi ? hi : v);
}

#define BSH 7      // 128 nodes per bucket
#define CHUNK 8192 // edges per scatter block

// ---------------- dtype detection ----------------

__global__ void detect_kernel(const unsigned int* __restrict__ gamma_raw,
                              const int* __restrict__ edge_raw, int* __restrict__ flags) {
    if (blockIdx.x == 0 && threadIdx.x == 0) {
        flags[0] = (gamma_raw[0] == 0x3F803F80u) ? 1 : 0;
        int is64 = 1;
        for (int i = 1; i <= 15; i += 2)
            if (edge_raw[i] != 0) is64 = 0;
        flags[1] = is64;
    }
}

// ---------------- param conversion ----------------

struct CvtPack {
    const void* src[10];
    void* dstA[10];
    void* dstB[10];
    int sz[10];
    int mode[10];
};

__global__ void cvt_params_kernel(CvtPack pp, const int* __restrict__ flags) {
    int b = blockIdx.x;
    int sz = pp.sz[b];
    int bf = flags[0];
    for (int i = threadIdx.x; i < sz; i += blockDim.x) {
        float w = bf ? __bfloat162float(((const __hip_bfloat16*)pp.src[b])[i])
                     : ((const float*)pp.src[b])[i];
        if (pp.mode[b] == 0) {
            ((float*)pp.dstA[b])[i] = w;
        } else {
            __hip_bfloat16 hi = __float2bfloat16(w);
            float r = w - __bfloat162float(hi);
            ((__hip_bfloat16*)pp.dstA[b])[i] = hi;
            ((__hip_bfloat16*)pp.dstB[b])[i] = __float2bfloat16(r);
        }
    }
}

// ---------------- CSR build: bucket sort ----------------

__global__ __launch_bounds__(256) void bucket_count_kernel(
    const int* __restrict__ edge, const int* __restrict__ flags,
    int* __restrict__ bucket_cnt, int E, int n, int NB) {
    __shared__ int hist[1024];
    for (int i = threadIdx.x; i < NB; i += 256) hist[i] = 0;
    __syncthreads();
    int base = blockIdx.x * CHUNK;
    int end = base + CHUNK < E ? base + CHUNK : E;
    int is64 = flags[1];
    for (int e = base + (int)threadIdx.x; e < end; e += 256) {
        int r = is64 ? edge[2 * e] : edge[e];
        r = clampi(r, 0, n - 1);
        atomicAdd(&hist[r >> BSH], 1);
    }
    __syncthreads();
    for (int i = threadIdx.x; i < NB; i += 256) {
        int v = hist[i];
        if (v) atomicAdd(&bucket_cnt[i], v);
    }
}

__global__ __launch_bounds__(1024) void bucket_scan_kernel(
    const int* __restrict__ bucket_cnt, int* __restrict__ bucket_base,
    int* __restrict__ bucket_cursor, int* __restrict__ row_ptr, int NB, int n, int E) {
    __shared__ int sh[1024];
    int t = threadIdx.x;
    int v = (t < NB) ? bucket_cnt[t] : 0;
    sh[t] = v;
    __syncthreads();
    for (int off = 1; off < 1024; off <<= 1) {
        int u = (t >= off) ? sh[t - off] : 0;
        __syncthreads();
        sh[t] += u;
        __syncthreads();
    }
    if (t < NB) {
        int base = sh[t] - v;  // exclusive
        bucket_base[t] = base;
        bucket_cursor[t] = base;
    }
    if (t == 0) row_ptr[n] = E;
}

__global__ __launch_bounds__(256) void bucket_scatter_kernel(
    const int* __restrict__ edge, const int* __restrict__ flags,
    int* __restrict__ bucket_cursor, unsigned* __restrict__ packed,
    int E, int n, int NB) {
    __shared__ int hist[1024];
    __shared__ int cur[1024];
    int t = threadIdx.x;
    for (int i = t; i < NB; i += 256) hist[i] = 0;
    __syncthreads();
    int base = blockIdx.x * CHUNK;
    int end = base + CHUNK < E ? base + CHUNK : E;
    int is64 = flags[1];
    for (int e = base + t; e < end; e += 256) {
        int r = is64 ? edge[2 * e] : edge[e];
        r = clampi(r, 0, n - 1);
        atomicAdd(&hist[r >> BSH], 1);
    }
    __syncthreads();
    for (int i = t; i < NB; i += 256) {
        int h = hist[i];
        cur[i] = h ? atomicAdd(&bucket_cursor[i], h) : 0;
    }
    __syncthreads();
    for (int e = base + t; e < end; e += 256) {
        int r = is64 ? edge[2 * e] : edge[e];
        int c = is64 ? edge[2 * (E + e)] : edge[E + e];
        r = clampi(r, 0, n - 1);
        c = clampi(c, 0, n - 1);
        int p = atomicAdd(&cur[r >> BSH], 1);
        packed[p] = ((unsigned)(r & 127) << 17) | (unsigned)c;  // col < 2^17
    }
}

#define SORT_CAP 4096
__global__ __launch_bounds__(256) void bucket_sort_kernel(
    const unsigned* __restrict__ packed, const int* __restrict__ bucket_base,
    const int* __restrict__ bucket_cnt, int* __restrict__ row_ptr,
    int* __restrict__ col_sorted, int n) {
    __shared__ int hist[128], cur[128];
    __shared__ int out[SORT_CAP];
    int b = blockIdx.x;
    int s = bucket_base[b];
    int cnt = bucket_cnt[b];
    int t = threadIdx.x;
    if (t < 128) hist[t] = 0;
    __syncthreads();
    for (int i = t; i < cnt; i += 256) atomicAdd(&hist[packed[s + i] >> 17], 1);
    __syncthreads();
    int orig = (t < 128) ? hist[t] : 0;
    for (int off = 1; off < 128; off <<= 1) {
        int u = (t < 128 && t >= off) ? hist[t - off] : 0;
        __syncthreads();
        if (t < 128) hist[t] += u;
        __syncthreads();
    }
    if (t < 128) {
        int ex = hist[t] - orig;  // exclusive
        cur[t] = ex;
        int node = (b << BSH) + t;
        if (node < n) row_ptr[node] = s + ex;
    }
    __syncthreads();
    if (cnt <= SORT_CAP) {
        for (int i = t; i < cnt; i += 256) {
            unsigned pk = packed[s + i];
            int p = atomicAdd(&cur[pk >> 17], 1);
            out[p] = (int)(pk & 0x1FFFFu);
        }
        __syncthreads();
        for (int i = t; i < cnt; i += 256) col_sorted[s + i] = out[i];
    } else {  // overflow fallback
        for (int i = t; i < cnt; i += 256) {
            unsigned pk = packed[s + i];
            int p = atomicAdd(&cur[pk >> 17], 1);
            col_sorted[s + p] = (int)(pk & 0x1FFFFu);
        }
    }
}

// ---------------- Aggregation: pure-sum gather ----------------
// One node per wave; s,e wave-uniform -> nfull guard-free iterations +
// one guarded tail. uint4 prefetch (4-reg copy), unpack at accumulate.

__device__ __forceinline__ void accum_bf8(uint4 u, float* acc) {
    acc[0] += bf_lo(u.x); acc[1] += bf_hi(u.x);
    acc[2] += bf_lo(u.y); acc[3] += bf_hi(u.y);
    acc[4] += bf_lo(u.z); acc[5] += bf_hi(u.z);
    acc[6] += bf_lo(u.w); acc[7] += bf_hi(u.w);
}

template <int D>
__device__ __forceinline__ void gather_bf(const __hip_bfloat16* __restrict__ base,
                                          const int* __restrict__ cols,
                                          int s, int e, int sub, float* acc) {
    constexpr int LPR = D / 8;
    constexpr int EPW = 64 / LPR;
    int cnt = e - s;
    int nfull = cnt / EPW;
    int rem = cnt - nfull * EPW;
    if (nfull > 0) {
        int k = s + sub;
        uint4 u = *reinterpret_cast<const uint4*>(base + (size_t)cols[k] * D);
        for (int it = 1; it < nfull; ++it) {
            k += EPW;
            uint4 un = *reinterpret_cast<const uint4*>(base + (size_t)cols[k] * D);
            accum_bf8(u, acc);
            u = un;
        }
        accum_bf8(u, acc);
    }
    if (sub < rem) {
        uint4 u = *reinterpret_cast<const uint4*>(
            base + (size_t)cols[s + nfull * EPW + sub] * D);
        accum_bf8(u, acc);
    }
}

template <int D>
__device__ __forceinline__ void gather_f32(const float* __restrict__ base,
                                           const int* __restrict__ cols,
                                           int s, int e, int sub, float* acc) {
    constexpr int LPR = D / 8;
    constexpr int EPW = 64 / LPR;
    int cnt = e - s;
    int nfull = cnt / EPW;
    int rem = cnt - nfull * EPW;
    int k = s + sub;
    for (int it = 0; it < nfull; ++it) {
        const float* p = base + (size_t)cols[k] * D;
        float4 a = *reinterpret_cast<const float4*>(p);
        float4 b = *reinterpret_cast<const float4*>(p + 4);
        acc[0] += a.x; acc[1] += a.y; acc[2] += a.z; acc[3] += a.w;
        acc[4] += b.x; acc[5] += b.y; acc[6] += b.z; acc[7] += b.w;
        k += EPW;
    }
    if (sub < rem) {
        const float* p = base + (size_t)cols[s + nfull * EPW + sub] * D;
        float4 a = *reinterpret_cast<const float4*>(p);
        float4 b = *reinterpret_cast<const float4*>(p + 4);
        acc[0] += a.x; acc[1] += a.y; acc[2] += a.z; acc[3] += a.w;
        acc[4] += b.x; acc[5] += b.y; acc[6] += b.z; acc[7] += b.w;
    }
}

template <int D, bool ADD_BIAS, bool OUT_FLAGDT>
__global__ __launch_bounds__(256) void agg_vec_kernel(
    const __hip_bfloat16* __restrict__ src, const int* __restrict__ row_ptr,
    const int* __restrict__ col_sorted, const float* __restrict__ bias,
    void* __restrict__ outp, const int* __restrict__ flags, int n) {
    constexpr int LPR = D / 8;
    int lane = threadIdx.x & 63;
    int node = blockIdx.x * 4 + (threadIdx.x >> 6);
    if (node >= n) return;
    int sub = lane / LPR;
    int c0 = (lane % LPR) * 8;

    int s = row_ptr[node];
    int e = row_ptr[node + 1];
    float acc[8];
#pragma unroll
    for (int j = 0; j < 8; ++j) acc[j] = 0.f;

    gather_bf<D>(src + c0, col_sorted, s, e, sub, acc);

#pragma unroll
    for (int j = 0; j < 8; ++j)
#pragma unroll
        for (int off = LPR; off < 64; off <<= 1) acc[j] += __shfl_xor(acc[j], off, 64);

    if (lane < LPR) {
        float recip = 1.0f / ((float)(e - s) + 1e-6f);
        float m[8];
#pragma unroll
        for (int j = 0; j < 8; ++j) {
            m[j] = acc[j] * recip;
            if (ADD_BIAS) m[j] += bias[c0 + j];
        }
        bool as_bf = !OUT_FLAGDT || flags[0];
        if (as_bf) {
            uint4 o;
            o.x = ((unsigned)f2bf(m[1]) << 16) | f2bf(m[0]);
            o.y = ((unsigned)f2bf(m[3]) << 16) | f2bf(m[2]);
            o.z = ((unsigned)f2bf(m[5]) << 16) | f2bf(m[4]);
            o.w = ((unsigned)f2bf(m[7]) << 16) | f2bf(m[6]);
            *reinterpret_cast<uint4*>((__hip_bfloat16*)outp + (size_t)node * D + c0) = o;
        } else {
            float* op = (float*)outp + (size_t)node * D + c0;
            *reinterpret_cast<float4*>(op) = make_float4(m[0], m[1], m[2], m[3]);
            *reinterpret_cast<float4*>(op + 4) = make_float4(m[4], m[5], m[6], m[7]);
        }
    }
}

// Layer-1 agg over raw x (dtype per flags), D=64, out bf16.
__global__ __launch_bounds__(256) void agg_x_kernel(
    const void* __restrict__ xsrc, const int* __restrict__ flags,
    const int* __restrict__ row_ptr, const int* __restrict__ col_sorted,
    __hip_bfloat16* __restrict__ out, int n) {
    constexpr int D = 64, LPR = 8;
    int lane = threadIdx.x & 63;
    int node = blockIdx.x * 4 + (threadIdx.x >> 6);
    if (node >= n) return;
    int sub = lane / LPR;
    int c0 = (lane % LPR) * 8;
    int s = row_ptr[node];
    int e = row_ptr[node + 1];
    float acc[8];
#pragma unroll
    for (int j = 0; j < 8; ++j) acc[j] = 0.f;

    if (flags[0])
        gather_bf<D>((const __hip_bfloat16*)xsrc + c0, col_sorted, s, e, sub, acc);
    else
        gather_f32<D>((const float*)xsrc + c0, col_sorted, s, e, sub, acc);

#pragma unroll
    for (int j = 0; j < 8; ++j)
#pragma unroll
        for (int off = LPR; off < 64; off <<= 1) acc[j] += __shfl_xor(acc[j], off, 64);

    if (lane < LPR) {
        float recip = 1.0f / ((float)(e - s) + 1e-6f);
        float m[8];
#pragma unroll
        for (int j = 0; j < 8; ++j) m[j] = acc[j] * recip;
        uint4 o;
        o.x = ((unsigned)f2bf(m[1]) << 16) | f2bf(m[0]);
        o.y = ((unsigned)f2bf(m[3]) << 16) | f2bf(m[2]);
        o.z = ((unsigned)f2bf(m[5]) << 16) | f2bf(m[4]);
        o.w = ((unsigned)f2bf(m[7]) << 16) | f2bf(m[6]);
        *reinterpret_cast<uint4*>(out + (size_t)node * D + c0) = o;
    }
}

// ---------------- MFMA GEMM, LDS-staged W ----------------
// 256 thr = 4 waves, 128 rows/block. W (hi+lo) staged in fragment order.
// APPLY_BN_A: A-load applies relu(a*scale+shift) per channel (once per row).

template <int D, int F, bool BIAS, bool APPLY_BN_A>
__global__ __launch_bounds__(256) void gemm_mfma_kernel(
    const __hip_bfloat16* __restrict__ A, const __hip_bfloat16* __restrict__ Whi,
    const __hip_bfloat16* __restrict__ Wlo, const float* __restrict__ bias,
    const float* __restrict__ bn_ss, __hip_bfloat16* __restrict__ C, int n) {
    constexpr int JT = F / 16;
    constexpr int KCH = D / 32;
    constexpr int NF = KCH * JT * 2;
    __shared__ uint4 wlds[NF * 64];  // max 64 KB (D=128,F=128)

    int t = threadIdx.x;
    for (int idx = t; idx < NF * 64; idx += 256) {
        int f = idx >> 6, ln = idx & 63;
        int kc = f / (JT * 2);
        int rem = f % (JT * 2);
        int jt = rem >> 1, h = rem & 1;
        int mm = ln & 15, qq = ln >> 4;
        const __hip_bfloat16* src =
            (h ? Wlo : Whi) + (size_t)(jt * 16 + mm) * D + kc * 32 + qq * 8;
        wlds[idx] = *reinterpret_cast<const uint4*>(src);
    }

    int lane = t & 63;
    int wave = t >> 6;
    int m = lane & 15;
    int quad = lane >> 4;
    int row_base = blockIdx.x * 128 + wave * 32;

    short8 af[2][KCH];
#pragma unroll
    for (int rs = 0; rs < 2; ++rs) {
        int r = row_base + rs * 16 + m;
        r = r < n ? r : n - 1;
        const __hip_bfloat16* ap = A + (size_t)r * D + quad * 8;
#pragma unroll
        for (int kc = 0; kc < KCH; ++kc) {
            union { uint4 u; short8 s; } tmp;
            tmp.u = *reinterpret_cast<const uint4*>(ap + kc * 32);
            af[rs][kc] = tmp.s;
        }
    }
    if (APPLY_BN_A) {
#pragma unroll
        for (int kc = 0; kc < KCH; ++kc) {
            int ch0 = kc * 32 + quad * 8;
            float sc[8], sh[8];
            *reinterpret_cast<float4*>(sc) = *reinterpret_cast<const float4*>(bn_ss + ch0);
            *reinterpret_cast<float4*>(sc + 4) = *reinterpret_cast<const float4*>(bn_ss + ch0 + 4);
            *reinterpret_cast<float4*>(sh) = *reinterpret_cast<const float4*>(bn_ss + 128 + ch0);
            *reinterpret_cast<float4*>(sh + 4) = *reinterpret_cast<const float4*>(bn_ss + 128 + ch0 + 4);
#pragma unroll
            for (int rs = 0; rs < 2; ++rs) {
#pragma unroll
                for (int j = 0; j < 8; ++j) {
                    float v = __uint_as_float(
                        ((unsigned)(unsigned short)af[rs][kc][j]) << 16);
                    v = fmaxf(fmaf(v, sc[j], sh[j]), 0.f);
                    af[rs][kc][j] = (short)f2bf(v);
                }
            }
        }
    }

    f32x4 acc[2][JT];
#pragma unroll
    for (int rs = 0; rs < 2; ++rs)
#pragma unroll
        for (int j = 0; j < JT; ++j) acc[rs][j] = {0.f, 0.f, 0.f, 0.f};

    __syncthreads();

#pragma unroll
    for (int kc = 0; kc < KCH; ++kc) {
#pragma unroll
        for (int jt = 0; jt < JT; ++jt) {
            int fb = (kc * JT + jt) * 2;
            union { uint4 u; short8 s; } bh, bl;
            bh.u = wlds[fb * 64 + lane];
            bl.u = wlds[(fb + 1) * 64 + lane];
            acc[0][jt] = __builtin_amdgcn_mfma_f32_16x16x32_bf16(af[0][kc], bh.s, acc[0][jt], 0, 0, 0);
            acc[1][jt] = __builtin_amdgcn_mfma_f32_16x16x32_bf16(af[1][kc], bh.s, acc[1][jt], 0, 0, 0);
            acc[0][jt] = __builtin_amdgcn_mfma_f32_16x16x32_bf16(af[0][kc], bl.s, acc[0][jt], 0, 0, 0);
            acc[1][jt] = __builtin_amdgcn_mfma_f32_16x16x32_bf16(af[1][kc], bl.s, acc[1][jt], 0, 0, 0);
        }
    }

#pragma unroll
    for (int rs = 0; rs < 2; ++rs) {
#pragma unroll
        for (int jt = 0; jt < JT; ++jt) {
            int col = jt * 16 + m;
            float bv = BIAS ? bias[col] : 0.f;
#pragma unroll
            for (int i = 0; i < 4; ++i) {
                int row = row_base + rs * 16 + quad * 4 + i;
                if (row < n)
                    C[(size_t)row * F + col] = __float2bfloat16(acc[rs][jt][i] + bv);
            }
        }
    }
}

// ---------------- BatchNorm ----------------

__global__ __launch_bounds__(256) void bn_stats_kernel(const __hip_bfloat16* __restrict__ X,
                                                       int n, float* __restrict__ sums) {
    __shared__ float red[2][16][128];
    int g = threadIdx.x & 15;
    int r0 = threadIdx.x >> 4;
    float s[8], q[8];
#pragma unroll
    for (int j = 0; j < 8; ++j) s[j] = q[j] = 0.f;
    for (int i = blockIdx.x * 16 + r0; i < n; i += gridDim.x * 16) {
        uint4 u = *reinterpret_cast<const uint4*>(X + (size_t)i * 128 + g * 8);
        float v[8];
        v[0] = bf_lo(u.x); v[1] = bf_hi(u.x);
        v[2] = bf_lo(u.y); v[3] = bf_hi(u.y);
        v[4] = bf_lo(u.z); v[5] = bf_hi(u.z);
        v[6] = bf_lo(u.w); v[7] = bf_hi(u.w);
#pragma unroll
        for (int j = 0; j < 8; ++j) {
            s[j] += v[j];
            q[j] += v[j] * v[j];
        }
    }
#pragma unroll
    for (int j = 0; j < 8; ++j) {
        red[0][r0][g * 8 + j] = s[j];
        red[1][r0][g * 8 + j] = q[j];
    }
    __syncthreads();
    for (int step = 8; step >= 1; step >>= 1) {
        if (r0 < step) {
#pragma unroll
            for (int j = 0; j < 8; ++j) {
                red[0][r0][g * 8 + j] += red[0][r0 + step][g * 8 + j];
                red[1][r0][g * 8 + j] += red[1][r0 + step][g * 8 + j];
            }
        }
        __syncthreads();
    }
    if (r0 == 0) {
#pragma unroll
        for (int j = 0; j < 8; ++j) {
            atomicAdd(&sums[g * 8 + j], red[0][0][g * 8 + j]);
            atomicAdd(&sums[128 + g * 8 + j], red[1][0][g * 8 + j]);
        }
    }
}

__global__ void bn_finalize_kernel(const float* __restrict__ sums,
                                   const float* __restrict__ gamma,
                                   const float* __restrict__ beta,
                                   float* __restrict__ ss, int n) {
    int c = threadIdx.x;  // 128
    float inv_n = 1.0f / (float)n;
    float mean = sums[c] * inv_n;
    float var = sums[128 + c] * inv_n - mean * mean;
    float inv = rsqrtf(var + 1e-5f);
    float scale = gamma[c] * inv;
    ss[c] = scale;
    ss[128 + c] = beta[c] - mean * scale;
}

// once-per-row BN apply + ReLU, in place on bf16 [n x 128]
__global__ __launch_bounds__(256) void bn_apply_kernel(__hip_bfloat16* __restrict__ X,
                                                       int ngroups,  // n*16
                                                       const float* __restrict__ ss) {
    __shared__ float lss[256];
    for (int i = threadIdx.x; i < 256; i += 256) lss[i] = ss[i];
    __syncthreads();
    int idx = blockIdx.x * 256 + threadIdx.x;
    int stride = gridDim.x * 256;
    for (; idx < ngroups; idx += stride) {
        int c0 = (idx & 15) * 8;
        uint4 u = *reinterpret_cast<uint4*>(X + (size_t)idx * 8);
        float v[8];
        v[0] = bf_lo(u.x); v[1] = bf_hi(u.x);
        v[2] = bf_lo(u.y); v[3] = bf_hi(u.y);
        v[4] = bf_lo(u.z); v[5] = bf_hi(u.z);
        v[6] = bf_lo(u.w); v[7] = bf_hi(u.w);
#pragma unroll
        for (int j = 0; j < 8; ++j) {
            float t = fmaf(v[j], lss[c0 + j], lss[128 + c0 + j]);
            v[j] = t > 0.f ? t : 0.f;
        }
        uint4 o;
        o.x = ((unsigned)f2bf(v[1]) << 16) | f2bf(v[0]);
        o.y = ((unsigned)f2bf(v[3]) << 16) | f2bf(v[2]);
        o.z = ((unsigned)f2bf(v[5]) << 16) | f2bf(v[4]);
        o.w = ((unsigned)f2bf(v[7]) << 16) | f2bf(v[6]);
        *reinterpret_cast<uint4*>(X + (size_t)idx * 8) = o;
    }
}

// ---------------- launch ----------------

extern "C" void kernel_launch(void* const* d_in, const int* in_sizes, int n_in,
                              void* d_out, int out_size, void* d_ws, size_t ws_size,
                              hipStream_t stream) {
    const void* x   = d_in[0];
    const int* edge = (const int*)d_in[1];

    int n = in_sizes[0] / 64;   // 100000
    int E = in_sizes[1] / 2;    // 1600000
    int NB = (n + 127) >> BSH;  // 782

    char* p = (char*)d_ws;
    auto carve = [&](size_t bytes) {
        char* q = p;
        p += (bytes + 255) & ~(size_t)255;
        return q;
    };
    int* flags      = (int*)carve(64);
    float* params   = (float*)carve(1024 * 4);
    __hip_bfloat16* Whi1 = (__hip_bfloat16*)carve(8192 * 2);
    __hip_bfloat16* Wlo1 = (__hip_bfloat16*)carve(8192 * 2);
    __hip_bfloat16* Whi2 = (__hip_bfloat16*)carve(16384 * 2);
    __hip_bfloat16* Wlo2 = (__hip_bfloat16*)carve(16384 * 2);
    __hip_bfloat16* Whi3 = (__hip_bfloat16*)carve(8192 * 2);
    __hip_bfloat16* Wlo3 = (__hip_bfloat16*)carve(8192 * 2);
    int* row_ptr    = (int*)carve((size_t)(n + 1) * 4);
    int* bucket_cnt = (int*)carve(1024 * 4);
    int* bucket_base= (int*)carve(1024 * 4);
    int* bucket_cur = (int*)carve(1024 * 4);
    float* bn_sums  = (float*)carve(256 * 4);
    float* bn_ss1   = (float*)carve(256 * 4);
    float* bn_ss2   = (float*)carve(256 * 4);
    unsigned* packed= (unsigned*)carve((size_t)E * 4);
    int* col_sorted = (int*)carve((size_t)E * 4);
    __hip_bfloat16* bufA = (__hip_bfloat16*)carve((size_t)n * 128 * 2);
    __hip_bfloat16* bufB = (__hip_bfloat16*)carve((size_t)n * 128 * 2);
    carve(65536);  // slack

    float* b1f = params;        // 128
    float* g1f = b1f + 128;     // 128
    float* be1f = g1f + 128;    // 128
    float* b2f = be1f + 128;    // 128
    float* g2f = b2f + 128;     // 128
    float* be2f = g2f + 128;    // 128
    float* b3f = be2f + 128;    // 64

    detect_kernel<<<1, 1, 0, stream>>>((const unsigned int*)d_in[4], edge, flags);

    CvtPack pp;
    const int pidx[10] = {2, 3, 4, 5, 6, 7, 8, 9, 10, 11};
    void* pa[10] = {Whi1, b1f, g1f, be1f, Whi2, b2f, g2f, be2f, Whi3, b3f};
    void* pb[10] = {Wlo1, nullptr, nullptr, nullptr, Wlo2, nullptr, nullptr, nullptr, Wlo3, nullptr};
    const int psz[10] = {8192, 128, 128, 128, 16384, 128, 128, 128, 8192, 64};
    const int pmode[10] = {1, 0, 0, 0, 1, 0, 0, 0, 1, 0};
    for (int i = 0; i < 10; ++i) {
        pp.src[i] = d_in[pidx[i]];
        pp.dstA[i] = pa[i];
        pp.dstB[i] = pb[i];
        pp.sz[i] = psz[i];
        pp.mode[i] = pmode[i];
    }
    cvt_params_kernel<<<10, 256, 0, stream>>>(pp, flags);

    // CSR build via bucket sort (block-reservation scatter)
    hipMemsetAsync(bucket_cnt, 0, 1024 * 4, stream);
    int nchunks = (E + CHUNK - 1) / CHUNK;
    bucket_count_kernel<<<nchunks, 256, 0, stream>>>(edge, flags, bucket_cnt, E, n, NB);
    bucket_scan_kernel<<<1, 1024, 0, stream>>>(bucket_cnt, bucket_base, bucket_cur, row_ptr, NB, n, E);
    bucket_scatter_kernel<<<nchunks, 256, 0, stream>>>(edge, flags, bucket_cur, packed, E, n, NB);
    bucket_sort_kernel<<<NB, 256, 0, stream>>>(packed, bucket_base, bucket_cnt, row_ptr, col_sorted, n);

    int gemm_grid = (n + 127) / 128;
    int agg_grid = (n + 3) / 4;

    // Layer 1: agg(x) D=64 -> bufA ; gemm -> bufB ; BN1 stats+apply
    agg_x_kernel<<<agg_grid, 256, 0, stream>>>(x, flags, row_ptr, col_sorted, bufA, n);
    gemm_mfma_kernel<64, 128, true, false><<<gemm_grid, 256, 0, stream>>>(
        bufA, Whi1, Wlo1, b1f, nullptr, bufB, n);
    hipMemsetAsync(bn_sums, 0, 256 * 4, stream);
    bn_stats_kernel<<<256, 256, 0, stream>>>(bufB, n, bn_sums);
    bn_finalize_kernel<<<1, 128, 0, stream>>>(bn_sums, g1f, be1f, bn_ss1, n);
    bn_apply_kernel<<<1024, 256, 0, stream>>>(bufB, n * 16, bn_ss1);

    // Layer 2: plain agg -> bufA ; gemm -> bufB ; BN2 stats (apply fused in gemm3)
    agg_vec_kernel<128, false, false><<<agg_grid, 256, 0, stream>>>(
        bufB, row_ptr, col_sorted, nullptr, bufA, flags, n);
    gemm_mfma_kernel<128, 128, true, false><<<gemm_grid, 256, 0, stream>>>(
        bufA, Whi2, Wlo2, b2f, nullptr, bufB, n);
    hipMemsetAsync(bn_sums, 0, 256 * 4, stream);
    bn_stats_kernel<<<256, 256, 0, stream>>>(bufB, n, bn_sums);
    bn_finalize_kernel<<<1, 128, 0, stream>>>(bn_sums, g2f, be2f, bn_ss2, n);

    // Layer 3 (reordered): gemm with fused BN2+ReLU on A (no bias) -> bufA[N x 64];
    // agg D=64 + bias -> d_out
    gemm_mfma_kernel<128, 64, false, true><<<gemm_grid, 256, 0, stream>>>(
        bufB, Whi3, Wlo3, nullptr, bn_ss2, bufA, n);
    agg_vec_kernel<64, true, true><<<agg_grid, 256, 0, stream>>>(
        bufA, row_ptr, col_sorted, b3f, d_out, flags, n);
}

// Round 9
// 482.396 us; speedup vs baseline: 1.1076x; 1.0987x over previous
//
#include <hip/hip_runtime.h>
#include <hip/hip_bf16.h>

// GCN: 3x (aggregate -> linear) with BN+ReLU between layers.
// R9: (1) per-node adjacency sorted by col (insertion sort in bucket_sort)
// so concurrent waves walk col-space in phase -> L2-resident band;
// (2) BN stats fused into gemm1/gemm2 epilogues (bn_stats passes deleted;
// quad-shuffle -> LDS reduce reusing W-staging LDS -> 256 global atomics/blk).
// Agg pure-sum gather as R8. CSR bucket sort as R5-R8.

using short8 = __attribute__((ext_vector_type(8))) short;
using f32x4  = __attribute__((ext_vector_type(4))) float;

__device__ __forceinline__ float bf_lo(unsigned int u) { return __uint_as_float(u << 16); }
__device__ __forceinline__ float bf_hi(unsigned int u) { return __uint_as_float(u & 0xffff0000u); }
__device__ __forceinline__ unsigned short f2bf(float f) {
    __hip_bfloat16 h = __float2bfloat16(f);
    return *reinterpret_cast<unsigned short*>(&h);
}
__device__ __forceinline__ int clampi(int v, int lo, int hi) {
    return v < lo ? lo : (v > hi ? hi : v);
}

#define BSH 7      // 128 nodes per bucket
#define CHUNK 8192 // edges per scatter block

// ---------------- dtype detection ----------------

__global__ void detect_kernel(const unsigned int* __restrict__ gamma_raw,
                              const int* __restrict__ edge_raw, int* __restrict__ flags) {
    if (blockIdx.x == 0 && threadIdx.x == 0) {
        flags[0] = (gamma_raw[0] == 0x3F803F80u) ? 1 : 0;
        int is64 = 1;
        for (int i = 1; i <= 15; i += 2)
            if (edge_raw[i] != 0) is64 = 0;
        flags[1] = is64;
    }
}

// ---------------- param conversion ----------------

struct CvtPack {
    const void* src[10];
    void* dstA[10];
    void* dstB[10];
    int sz[10];
    int mode[10];
};

__global__ void cvt_params_kernel(CvtPack pp, const int* __restrict__ flags) {
    int b = blockIdx.x;
    int sz = pp.sz[b];
    int bf = flags[0];
    for (int i = threadIdx.x; i < sz; i += blockDim.x) {
        float w = bf ? __bfloat162float(((const __hip_bfloat16*)pp.src[b])[i])
                     : ((const float*)pp.src[b])[i];
        if (pp.mode[b] == 0) {
            ((float*)pp.dstA[b])[i] = w;
        } else {
            __hip_bfloat16 hi = __float2bfloat16(w);
            float r = w - __bfloat162float(hi);
            ((__hip_bfloat16*)pp.dstA[b])[i] = hi;
            ((__hip_bfloat16*)pp.dstB[b])[i] = __float2bfloat16(r);
        }
    }
}

// ---------------- CSR build: bucket sort ----------------

__global__ __launch_bounds__(256) void bucket_count_kernel(
    const int* __restrict__ edge, const int* __restrict__ flags,
    int* __restrict__ bucket_cnt, int E, int n, int NB) {
    __shared__ int hist[1024];
    for (int i = threadIdx.x; i < NB; i += 256) hist[i] = 0;
    __syncthreads();
    int base = blockIdx.x * CHUNK;
    int end = base + CHUNK < E ? base + CHUNK : E;
    int is64 = flags[1];
    for (int e = base + (int)threadIdx.x; e < end; e += 256) {
        int r = is64 ? edge[2 * e] : edge[e];
        r = clampi(r, 0, n - 1);
        atomicAdd(&hist[r >> BSH], 1);
    }
    __syncthreads();
    for (int i = threadIdx.x; i < NB; i += 256) {
        int v = hist[i];
        if (v) atomicAdd(&bucket_cnt[i], v);
    }
}

__global__ __launch_bounds__(1024) void bucket_scan_kernel(
    const int* __restrict__ bucket_cnt, int* __restrict__ bucket_base,
    int* __restrict__ bucket_cursor, int* __restrict__ row_ptr, int NB, int n, int E) {
    __shared__ int sh[1024];
    int t = threadIdx.x;
    int v = (t < NB) ? bucket_cnt[t] : 0;
    sh[t] = v;
    __syncthreads();
    for (int off = 1; off < 1024; off <<= 1) {
        int u = (t >= off) ? sh[t - off] : 0;
        __syncthreads();
        sh[t] += u;
        __syncthreads();
    }
    if (t < NB) {
        int base = sh[t] - v;  // exclusive
        bucket_base[t] = base;
        bucket_cursor[t] = base;
    }
    if (t == 0) row_ptr[n] = E;
}

__global__ __launch_bounds__(256) void bucket_scatter_kernel(
    const int* __restrict__ edge, const int* __restrict__ flags,
    int* __restrict__ bucket_cursor, unsigned* __restrict__ packed,
    int E, int n, int NB) {
    __shared__ int hist[1024];
    __shared__ int cur[1024];
    int t = threadIdx.x;
    for (int i = t; i < NB; i += 256) hist[i] = 0;
    __syncthreads();
    int base = blockIdx.x * CHUNK;
    int end = base + CHUNK < E ? base + CHUNK : E;
    int is64 = flags[1];
    for (int e = base + t; e < end; e += 256) {
        int r = is64 ? edge[2 * e] : edge[e];
        r = clampi(r, 0, n - 1);
        atomicAdd(&hist[r >> BSH], 1);
    }
    __syncthreads();
    for (int i = t; i < NB; i += 256) {
        int h = hist[i];
        cur[i] = h ? atomicAdd(&bucket_cursor[i], h) : 0;
    }
    __syncthreads();
    for (int e = base + t; e < end; e += 256) {
        int r = is64 ? edge[2 * e] : edge[e];
        int c = is64 ? edge[2 * (E + e)] : edge[E + e];
        r = clampi(r, 0, n - 1);
        c = clampi(c, 0, n - 1);
        int p = atomicAdd(&cur[r >> BSH], 1);
        packed[p] = ((unsigned)(r & 127) << 17) | (unsigned)c;  // col < 2^17
    }
}

#define SORT_CAP 4096
__global__ __launch_bounds__(256) void bucket_sort_kernel(
    const unsigned* __restrict__ packed, const int* __restrict__ bucket_base,
    const int* __restrict__ bucket_cnt, int* __restrict__ row_ptr,
    int* __restrict__ col_sorted, int n) {
    __shared__ int hist[128], cur[128];
    __shared__ int out[SORT_CAP];
    int b = blockIdx.x;
    int s = bucket_base[b];
    int cnt = bucket_cnt[b];
    int t = threadIdx.x;
    if (t < 128) hist[t] = 0;
    __syncthreads();
    for (int i = t; i < cnt; i += 256) atomicAdd(&hist[packed[s + i] >> 17], 1);
    __syncthreads();
    int orig = (t < 128) ? hist[t] : 0;
    for (int off = 1; off < 128; off <<= 1) {
        int u = (t < 128 && t >= off) ? hist[t - off] : 0;
        __syncthreads();
        if (t < 128) hist[t] += u;
        __syncthreads();
    }
    int ex = (t < 128) ? hist[t] - orig : 0;  // exclusive start of node t's segment
    if (t < 128) {
        cur[t] = ex;
        int node = (b << BSH) + t;
        if (node < n) row_ptr[node] = s + ex;
    }
    __syncthreads();
    if (cnt <= SORT_CAP) {
        for (int i = t; i < cnt; i += 256) {
            unsigned pk = packed[s + i];
            int p = atomicAdd(&cur[pk >> 17], 1);
            out[p] = (int)(pk & 0x1FFFFu);
        }
        __syncthreads();
        // per-node insertion sort of cols (ascending): aligns concurrent
        // waves' gather progress -> L2-resident band in the agg kernels.
        if (t < 128 && orig > 1) {
            int s0 = ex, e0 = ex + orig;
            for (int i = s0 + 1; i < e0; ++i) {
                int key = out[i];
                int j = i - 1;
                while (j >= s0 && out[j] > key) {
                    out[j + 1] = out[j];
                    --j;
                }
                out[j + 1] = key;
            }
        }
        __syncthreads();
        for (int i = t; i < cnt; i += 256) col_sorted[s + i] = out[i];
    } else {  // overflow fallback (unsorted cols; correctness preserved)
        for (int i = t; i < cnt; i += 256) {
            unsigned pk = packed[s + i];
            int p = atomicAdd(&cur[pk >> 17], 1);
            col_sorted[s + p] = (int)(pk & 0x1FFFFu);
        }
    }
}

// ---------------- Aggregation: pure-sum gather ----------------

__device__ __forceinline__ void accum_bf8(uint4 u, float* acc) {
    acc[0] += bf_lo(u.x); acc[1] += bf_hi(u.x);
    acc[2] += bf_lo(u.y); acc[3] += bf_hi(u.y);
    acc[4] += bf_lo(u.z); acc[5] += bf_hi(u.z);
    acc[6] += bf_lo(u.w); acc[7] += bf_hi(u.w);
}

template <int D>
__device__ __forceinline__ void gather_bf(const __hip_bfloat16* __restrict__ base,
                                          const int* __restrict__ cols,
                                          int s, int e, int sub, float* acc) {
    constexpr int LPR = D / 8;
    constexpr int EPW = 64 / LPR;
    int cnt = e - s;
    int nfull = cnt / EPW;
    int rem = cnt - nfull * EPW;
    if (nfull > 0) {
        int k = s + sub;
        uint4 u = *reinterpret_cast<const uint4*>(base + (size_t)cols[k] * D);
        for (int it = 1; it < nfull; ++it) {
            k += EPW;
            uint4 un = *reinterpret_cast<const uint4*>(base + (size_t)cols[k] * D);
            accum_bf8(u, acc);
            u = un;
        }
        accum_bf8(u, acc);
    }
    if (sub < rem) {
        uint4 u = *reinterpret_cast<const uint4*>(
            base + (size_t)cols[s + nfull * EPW + sub] * D);
        accum_bf8(u, acc);
    }
}

template <int D>
__device__ __forceinline__ void gather_f32(const float* __restrict__ base,
                                           const int* __restrict__ cols,
                                           int s, int e, int sub, float* acc) {
    constexpr int LPR = D / 8;
    constexpr int EPW = 64 / LPR;
    int cnt = e - s;
    int nfull = cnt / EPW;
    int rem = cnt - nfull * EPW;
    int k = s + sub;
    for (int it = 0; it < nfull; ++it) {
        const float* p = base + (size_t)cols[k] * D;
        float4 a = *reinterpret_cast<const float4*>(p);
        float4 b = *reinterpret_cast<const float4*>(p + 4);
        acc[0] += a.x; acc[1] += a.y; acc[2] += a.z; acc[3] += a.w;
        acc[4] += b.x; acc[5] += b.y; acc[6] += b.z; acc[7] += b.w;
        k += EPW;
    }
    if (sub < rem) {
        const float* p = base + (size_t)cols[s + nfull * EPW + sub] * D;
        float4 a = *reinterpret_cast<const float4*>(p);
        float4 b = *reinterpret_cast<const float4*>(p + 4);
        acc[0] += a.x; acc[1] += a.y; acc[2] += a.z; acc[3] += a.w;
        acc[4] += b.x; acc[5] += b.y; acc[6] += b.z; acc[7] += b.w;
    }
}

template <int D, bool ADD_BIAS, bool OUT_FLAGDT>
__global__ __launch_bounds__(256) void agg_vec_kernel(
    const __hip_bfloat16* __restrict__ src, const int* __restrict__ row_ptr,
    const int* __restrict__ col_sorted, const float* __restrict__ bias,
    void* __restrict__ outp, const int* __restrict__ flags, int n) {
    constexpr int LPR = D / 8;
    int lane = threadIdx.x & 63;
    int node = blockIdx.x * 4 + (threadIdx.x >> 6);
    if (node >= n) return;
    int sub = lane / LPR;
    int c0 = (lane % LPR) * 8;

    int s = row_ptr[node];
    int e = row_ptr[node + 1];
    float acc[8];
#pragma unroll
    for (int j = 0; j < 8; ++j) acc[j] = 0.f;

    gather_bf<D>(src + c0, col_sorted, s, e, sub, acc);

#pragma unroll
    for (int j = 0; j < 8; ++j)
#pragma unroll
        for (int off = LPR; off < 64; off <<= 1) acc[j] += __shfl_xor(acc[j], off, 64);

    if (lane < LPR) {
        float recip = 1.0f / ((float)(e - s) + 1e-6f);
        float m[8];
#pragma unroll
        for (int j = 0; j < 8; ++j) {
            m[j] = acc[j] * recip;
            if (ADD_BIAS) m[j] += bias[c0 + j];
        }
        bool as_bf = !OUT_FLAGDT || flags[0];
        if (as_bf) {
            uint4 o;
            o.x = ((unsigned)f2bf(m[1]) << 16) | f2bf(m[0]);
            o.y = ((unsigned)f2bf(m[3]) << 16) | f2bf(m[2]);
            o.z = ((unsigned)f2bf(m[5]) << 16) | f2bf(m[4]);
            o.w = ((unsigned)f2bf(m[7]) << 16) | f2bf(m[6]);
            *reinterpret_cast<uint4*>((__hip_bfloat16*)outp + (size_t)node * D + c0) = o;
        } else {
            float* op = (float*)outp + (size_t)node * D + c0;
            *reinterpret_cast<float4*>(op) = make_float4(m[0], m[1], m[2], m[3]);
            *reinterpret_cast<float4*>(op + 4) = make_float4(m[4], m[5], m[6], m[7]);
        }
    }
}

// Layer-1 agg over raw x (dtype per flags), D=64, out bf16.
__global__ __launch_bounds__(256) void agg_x_kernel(
    const void* __restrict__ xsrc, const int* __restrict__ flags,
    const int* __restrict__ row_ptr, const int* __restrict__ col_sorted,
    __hip_bfloat16* __restrict__ out, int n) {
    constexpr int D = 64, LPR = 8;
    int lane = threadIdx.x & 63;
    int node = blockIdx.x * 4 + (threadIdx.x >> 6);
    if (node >= n) return;
    int sub = lane / LPR;
    int c0 = (lane % LPR) * 8;
    int s = row_ptr[node];
    int e = row_ptr[node + 1];
    float acc[8];
#pragma unroll
    for (int j = 0; j < 8; ++j) acc[j] = 0.f;

    if (flags[0])
        gather_bf<D>((const __hip_bfloat16*)xsrc + c0, col_sorted, s, e, sub, acc);
    else
        gather_f32<D>((const float*)xsrc + c0, col_sorted, s, e, sub, acc);

#pragma unroll
    for (int j = 0; j < 8; ++j)
#pragma unroll
        for (int off = LPR; off < 64; off <<= 1) acc[j] += __shfl_xor(acc[j], off, 64);

    if (lane < LPR) {
        float recip = 1.0f / ((float)(e - s) + 1e-6f);
        float m[8];
#pragma unroll
        for (int j = 0; j < 8; ++j) m[j] = acc[j] * recip;
        uint4 o;
        o.x = ((unsigned)f2bf(m[1]) << 16) | f2bf(m[0]);
        o.y = ((unsigned)f2bf(m[3]) << 16) | f2bf(m[2]);
        o.z = ((unsigned)f2bf(m[5]) << 16) | f2bf(m[4]);
        o.w = ((unsigned)f2bf(m[7]) << 16) | f2bf(m[6]);
        *reinterpret_cast<uint4*>(out + (size_t)node * D + c0) = o;
    }
}

// ---------------- MFMA GEMM, LDS-staged W, optional fused BN stats ----------------
// 256 thr = 4 waves, 128 rows/block. W (hi+lo) staged in fragment order.
// APPLY_BN_A: A-load applies relu(a*scale+shift) (once per row).
// STATS: epilogue accumulates per-column sum/sumsq of (acc+bias) into
// stats[0:F) / stats[F:2F) via quad-shuffle -> LDS (reusing wlds) -> global.

template <int D, int F, bool BIAS, bool APPLY_BN_A, bool STATS>
__global__ __launch_bounds__(256) void gemm_mfma_kernel(
    const __hip_bfloat16* __restrict__ A, const __hip_bfloat16* __restrict__ Whi,
    const __hip_bfloat16* __restrict__ Wlo, const float* __restrict__ bias,
    const float* __restrict__ bn_ss, float* __restrict__ stats,
    __hip_bfloat16* __restrict__ C, int n) {
    constexpr int JT = F / 16;
    constexpr int KCH = D / 32;
    constexpr int NF = KCH * JT * 2;
    __shared__ uint4 wlds[NF * 64];  // max 64 KB (D=128,F=128); reused for stats

    int t = threadIdx.x;
    for (int idx = t; idx < NF * 64; idx += 256) {
        int f = idx >> 6, ln = idx & 63;
        int kc = f / (JT * 2);
        int rem = f % (JT * 2);
        int jt = rem >> 1, h = rem & 1;
        int mm = ln & 15, qq = ln >> 4;
        const __hip_bfloat16* src =
            (h ? Wlo : Whi) + (size_t)(jt * 16 + mm) * D + kc * 32 + qq * 8;
        wlds[idx] = *reinterpret_cast<const uint4*>(src);
    }

    int lane = t & 63;
    int wave = t >> 6;
    int m = lane & 15;
    int quad = lane >> 4;
    int row_base = blockIdx.x * 128 + wave * 32;

    short8 af[2][KCH];
#pragma unroll
    for (int rs = 0; rs < 2; ++rs) {
        int r = row_base + rs * 16 + m;
        r = r < n ? r : n - 1;
        const __hip_bfloat16* ap = A + (size_t)r * D + quad * 8;
#pragma unroll
        for (int kc = 0; kc < KCH; ++kc) {
            union { uint4 u; short8 s; } tmp;
            tmp.u = *reinterpret_cast<const uint4*>(ap + kc * 32);
            af[rs][kc] = tmp.s;
        }
    }
    if (APPLY_BN_A) {
#pragma unroll
        for (int kc = 0; kc < KCH; ++kc) {
            int ch0 = kc * 32 + quad * 8;
            float sc[8], sh[8];
            *reinterpret_cast<float4*>(sc) = *reinterpret_cast<const float4*>(bn_ss + ch0);
            *reinterpret_cast<float4*>(sc + 4) = *reinterpret_cast<const float4*>(bn_ss + ch0 + 4);
            *reinterpret_cast<float4*>(sh) = *reinterpret_cast<const float4*>(bn_ss + 128 + ch0);
            *reinterpret_cast<float4*>(sh + 4) = *reinterpret_cast<const float4*>(bn_ss + 128 + ch0 + 4);
#pragma unroll
            for (int rs = 0; rs < 2; ++rs) {
#pragma unroll
                for (int j = 0; j < 8; ++j) {
                    float v = __uint_as_float(
                        ((unsigned)(unsigned short)af[rs][kc][j]) << 16);
                    v = fmaxf(fmaf(v, sc[j], sh[j]), 0.f);
                    af[rs][kc][j] = (short)f2bf(v);
                }
            }
        }
    }

    f32x4 acc[2][JT];
#pragma unroll
    for (int rs = 0; rs < 2; ++rs)
#pragma unroll
        for (int j = 0; j < JT; ++j) acc[rs][j] = {0.f, 0.f, 0.f, 0.f};

    __syncthreads();

#pragma unroll
    for (int kc = 0; kc < KCH; ++kc) {
#pragma unroll
        for (int jt = 0; jt < JT; ++jt) {
            int fb = (kc * JT + jt) * 2;
            union { uint4 u; short8 s; } bh, bl;
            bh.u = wlds[fb * 64 + lane];
            bl.u = wlds[(fb + 1) * 64 + lane];
            acc[0][jt] = __builtin_amdgcn_mfma_f32_16x16x32_bf16(af[0][kc], bh.s, acc[0][jt], 0, 0, 0);
            acc[1][jt] = __builtin_amdgcn_mfma_f32_16x16x32_bf16(af[1][kc], bh.s, acc[1][jt], 0, 0, 0);
            acc[0][jt] = __builtin_amdgcn_mfma_f32_16x16x32_bf16(af[0][kc], bl.s, acc[0][jt], 0, 0, 0);
            acc[1][jt] = __builtin_amdgcn_mfma_f32_16x16x32_bf16(af[1][kc], bl.s, acc[1][jt], 0, 0, 0);
        }
    }

#pragma unroll
    for (int rs = 0; rs < 2; ++rs) {
#pragma unroll
        for (int jt = 0; jt < JT; ++jt) {
            int col = jt * 16 + m;
            float bv = BIAS ? bias[col] : 0.f;
#pragma unroll
            for (int i = 0; i < 4; ++i) {
                int row = row_base + rs * 16 + quad * 4 + i;
                if (row < n)
                    C[(size_t)row * F + col] = __float2bfloat16(acc[rs][jt][i] + bv);
            }
        }
    }

    if (STATS) {
        float* slds = reinterpret_cast<float*>(wlds);  // 2*F floats (<= LDS used)
        __syncthreads();  // all waves done reading wlds
        for (int i = t; i < 2 * F; i += 256) slds[i] = 0.f;
        __syncthreads();
#pragma unroll
        for (int jt = 0; jt < JT; ++jt) {
            int col = jt * 16 + m;
            float bv = BIAS ? bias[col] : 0.f;
            float s = 0.f, q = 0.f;
#pragma unroll
            for (int rs = 0; rs < 2; ++rs) {
#pragma unroll
                for (int i = 0; i < 4; ++i) {
                    int row = row_base + rs * 16 + quad * 4 + i;
                    if (row < n) {
                        float v = acc[rs][jt][i] + bv;
                        s += v;
                        q += v * v;
                    }
                }
            }
            // reduce across quads (lanes m, m+16, m+32, m+48)
            s += __shfl_xor(s, 16, 64); s += __shfl_xor(s, 32, 64);
            q += __shfl_xor(q, 16, 64); q += __shfl_xor(q, 32, 64);
            if (quad == 0) {
                atomicAdd(&slds[col], s);
                atomicAdd(&slds[F + col], q);
            }
        }
        __syncthreads();
        for (int i = t; i < 2 * F; i += 256) atomicAdd(&stats[i], slds[i]);
    }
}

// ---------------- BatchNorm ----------------

__global__ void bn_finalize_kernel(const float* __restrict__ sums,
                                   const float* __restrict__ gamma,
                                   const float* __restrict__ beta,
                                   float* __restrict__ ss, int n) {
    int c = threadIdx.x;  // 128
    float inv_n = 1.0f / (float)n;
    float mean = sums[c] * inv_n;
    float var = sums[128 + c] * inv_n - mean * mean;
    float inv = rsqrtf(var + 1e-5f);
    float scale = gamma[c] * inv;
    ss[c] = scale;
    ss[128 + c] = beta[c] - mean * scale;
}

// once-per-row BN apply + ReLU, in place on bf16 [n x 128]
__global__ __launch_bounds__(256) void bn_apply_kernel(__hip_bfloat16* __restrict__ X,
                                                       int ngroups,  // n*16
                                                       const float* __restrict__ ss) {
    __shared__ float lss[256];
    for (int i = threadIdx.x; i < 256; i += 256) lss[i] = ss[i];
    __syncthreads();
    int idx = blockIdx.x * 256 + threadIdx.x;
    int stride = gridDim.x * 256;
    for (; idx < ngroups; idx += stride) {
        int c0 = (idx & 15) * 8;
        uint4 u = *reinterpret_cast<uint4*>(X + (size_t)idx * 8);
        float v[8];
        v[0] = bf_lo(u.x); v[1] = bf_hi(u.x);
        v[2] = bf_lo(u.y); v[3] = bf_hi(u.y);
        v[4] = bf_lo(u.z); v[5] = bf_hi(u.z);
        v[6] = bf_lo(u.w); v[7] = bf_hi(u.w);
#pragma unroll
        for (int j = 0; j < 8; ++j) {
            float t = fmaf(v[j], lss[c0 + j], lss[128 + c0 + j]);
            v[j] = t > 0.f ? t : 0.f;
        }
        uint4 o;
        o.x = ((unsigned)f2bf(v[1]) << 16) | f2bf(v[0]);
        o.y = ((unsigned)f2bf(v[3]) << 16) | f2bf(v[2]);
        o.z = ((unsigned)f2bf(v[5]) << 16) | f2bf(v[4]);
        o.w = ((unsigned)f2bf(v[7]) << 16) | f2bf(v[6]);
        *reinterpret_cast<uint4*>(X + (size_t)idx * 8) = o;
    }
}

// ---------------- launch ----------------

extern "C" void kernel_launch(void* const* d_in, const int* in_sizes, int n_in,
                              void* d_out, int out_size, void* d_ws, size_t ws_size,
                              hipStream_t stream) {
    const void* x   = d_in[0];
    const int* edge = (const int*)d_in[1];

    int n = in_sizes[0] / 64;   // 100000
    int E = in_sizes[1] / 2;    // 1600000
    int NB = (n + 127) >> BSH;  // 782

    char* p = (char*)d_ws;
    auto carve = [&](size_t bytes) {
        char* q = p;
        p += (bytes + 255) & ~(size_t)255;
        return q;
    };
    int* flags      = (int*)carve(64);
    float* params   = (float*)carve(1024 * 4);
    __hip_bfloat16* Whi1 = (__hip_bfloat16*)carve(8192 * 2);
    __hip_bfloat16* Wlo1 = (__hip_bfloat16*)carve(8192 * 2);
    __hip_bfloat16* Whi2 = (__hip_bfloat16*)carve(16384 * 2);
    __hip_bfloat16* Wlo2 = (__hip_bfloat16*)carve(16384 * 2);
    __hip_bfloat16* Whi3 = (__hip_bfloat16*)carve(8192 * 2);
    __hip_bfloat16* Wlo3 = (__hip_bfloat16*)carve(8192 * 2);
    int* row_ptr    = (int*)carve((size_t)(n + 1) * 4);
    int* bucket_cnt = (int*)carve(1024 * 4);
    int* bucket_base= (int*)carve(1024 * 4);
    int* bucket_cur = (int*)carve(1024 * 4);
    float* bn_sums  = (float*)carve(512 * 4);   // [0:256) layer1, [256:512) layer2
    float* bn_ss1   = (float*)carve(256 * 4);
    float* bn_ss2   = (float*)carve(256 * 4);
    unsigned* packed= (unsigned*)carve((size_t)E * 4);
    int* col_sorted = (int*)carve((size_t)E * 4);
    __hip_bfloat16* bufA = (__hip_bfloat16*)carve((size_t)n * 128 * 2);
    __hip_bfloat16* bufB = (__hip_bfloat16*)carve((size_t)n * 128 * 2);
    carve(65536);  // slack

    float* b1f = params;        // 128
    float* g1f = b1f + 128;     // 128
    float* be1f = g1f + 128;    // 128
    float* b2f = be1f + 128;    // 128
    float* g2f = b2f + 128;     // 128
    float* be2f = g2f + 128;    // 128
    float* b3f = be2f + 128;    // 64

    detect_kernel<<<1, 1, 0, stream>>>((const unsigned int*)d_in[4], edge, flags);

    CvtPack pp;
    const int pidx[10] = {2, 3, 4, 5, 6, 7, 8, 9, 10, 11};
    void* pa[10] = {Whi1, b1f, g1f, be1f, Whi2, b2f, g2f, be2f, Whi3, b3f};
    void* pb[10] = {Wlo1, nullptr, nullptr, nullptr, Wlo2, nullptr, nullptr, nullptr, Wlo3, nullptr};
    const int psz[10] = {8192, 128, 128, 128, 16384, 128, 128, 128, 8192, 64};
    const int pmode[10] = {1, 0, 0, 0, 1, 0, 0, 0, 1, 0};
    for (int i = 0; i < 10; ++i) {
        pp.src[i] = d_in[pidx[i]];
        pp.dstA[i] = pa[i];
        pp.dstB[i] = pb[i];
        pp.sz[i] = psz[i];
        pp.mode[i] = pmode[i];
    }
    cvt_params_kernel<<<10, 256, 0, stream>>>(pp, flags);

    // CSR build via bucket sort (block-reservation scatter, col-sorted adjacency)
    hipMemsetAsync(bucket_cnt, 0, 1024 * 4, stream);
    hipMemsetAsync(bn_sums, 0, 512 * 4, stream);
    int nchunks = (E + CHUNK - 1) / CHUNK;
    bucket_count_kernel<<<nchunks, 256, 0, stream>>>(edge, flags, bucket_cnt, E, n, NB);
    bucket_scan_kernel<<<1, 1024, 0, stream>>>(bucket_cnt, bucket_base, bucket_cur, row_ptr, NB, n, E);
    bucket_scatter_kernel<<<nchunks, 256, 0, stream>>>(edge, flags, bucket_cur, packed, E, n, NB);
    bucket_sort_kernel<<<NB, 256, 0, stream>>>(packed, bucket_base, bucket_cnt, row_ptr, col_sorted, n);

    int gemm_grid = (n + 127) / 128;
    int agg_grid = (n + 3) / 4;

    // Layer 1: agg(x) -> bufA ; gemm (+fused BN1 stats) -> bufB ; finalize+apply
    agg_x_kernel<<<agg_grid, 256, 0, stream>>>(x, flags, row_ptr, col_sorted, bufA, n);
    gemm_mfma_kernel<64, 128, true, false, true><<<gemm_grid, 256, 0, stream>>>(
        bufA, Whi1, Wlo1, b1f, nullptr, bn_sums, bufB, n);
    bn_finalize_kernel<<<1, 128, 0, stream>>>(bn_sums, g1f, be1f, bn_ss1, n);
    bn_apply_kernel<<<1024, 256, 0, stream>>>(bufB, n * 16, bn_ss1);

    // Layer 2: agg -> bufA ; gemm (+fused BN2 stats) -> bufB ; finalize
    agg_vec_kernel<128, false, false><<<agg_grid, 256, 0, stream>>>(
        bufB, row_ptr, col_sorted, nullptr, bufA, flags, n);
    gemm_mfma_kernel<128, 128, true, false, true><<<gemm_grid, 256, 0, stream>>>(
        bufA, Whi2, Wlo2, b2f, nullptr, bn_sums + 256, bufB, n);
    bn_finalize_kernel<<<1, 128, 0, stream>>>(bn_sums + 256, g2f, be2f, bn_ss2, n);

    // Layer 3 (reordered): gemm with fused BN2+ReLU on A (no bias) -> bufA[N x 64];
    // agg D=64 + bias -> d_out
    gemm_mfma_kernel<128, 64, false, true, false><<<gemm_grid, 256, 0, stream>>>(
        bufB, Whi3, Wlo3, nullptr, bn_ss2, nullptr, bufA, n);
    agg_vec_kernel<64, true, true><<<agg_grid, 256, 0, stream>>>(
        bufA, row_ptr, col_sorted, b3f, d_out, flags, n);
}

// Round 10
// 434.361 us; speedup vs baseline: 1.2300x; 1.1106x over previous
//
#include <hip/hip_runtime.h>
#include <hip/hip_bf16.h>

// GCN: 3x (aggregate -> linear) with BN+ReLU between layers.
// R10: agg gather batches 4 independent uint4 loads per step (4-deep MLP,
// no pipeline copies) and accumulates in packed f32x2 (v_pk_add_f32).
// R9's per-node col sort removed (falsified: FETCH unchanged). BN stats
// stay fused in gemm epilogues. CSR bucket sort as R5-R9.

using short8 = __attribute__((ext_vector_type(8))) short;
using f32x4  = __attribute__((ext_vector_type(4))) float;
using f32x2  = __attribute__((ext_vector_type(2))) float;

__device__ __forceinline__ float bf_lo(unsigned int u) { return __uint_as_float(u << 16); }
__device__ __forceinline__ float bf_hi(unsigned int u) { return __uint_as_float(u & 0xffff0000u); }
__device__ __forceinline__ f32x2 bfpair(unsigned int u) {
    f32x2 r;
    r.x = __uint_as_float(u << 16);
    r.y = __uint_as_float(u & 0xffff0000u);
    return r;
}
__device__ __forceinline__ unsigned short f2bf(float f) {
    __hip_bfloat16 h = __float2bfloat16(f);
    return *reinterpret_cast<unsigned short*>(&h);
}
__device__ __forceinline__ int clampi(int v, int lo, int hi) {
    return v < lo ? lo : (v > hi ? hi : v);
}

#define BSH 7      // 128 nodes per bucket
#define CHUNK 8192 // edges per scatter block

// ---------------- dtype detection ----------------

__global__ void detect_kernel(const unsigned int* __restrict__ gamma_raw,
                              const int* __restrict__ edge_raw, int* __restrict__ flags) {
    if (blockIdx.x == 0 && threadIdx.x == 0) {
        flags[0] = (gamma_raw[0] == 0x3F803F80u) ? 1 : 0;
        int is64 = 1;
        for (int i = 1; i <= 15; i += 2)
            if (edge_raw[i] != 0) is64 = 0;
        flags[1] = is64;
    }
}

// ---------------- param conversion ----------------

struct CvtPack {
    const void* src[10];
    void* dstA[10];
    void* dstB[10];
    int sz[10];
    int mode[10];
};

__global__ void cvt_params_kernel(CvtPack pp, const int* __restrict__ flags) {
    int b = blockIdx.x;
    int sz = pp.sz[b];
    int bf = flags[0];
    for (int i = threadIdx.x; i < sz; i += blockDim.x) {
        float w = bf ? __bfloat162float(((const __hip_bfloat16*)pp.src[b])[i])
                     : ((const float*)pp.src[b])[i];
        if (pp.mode[b] == 0) {
            ((float*)pp.dstA[b])[i] = w;
        } else {
            __hip_bfloat16 hi = __float2bfloat16(w);
            float r = w - __bfloat162float(hi);
            ((__hip_bfloat16*)pp.dstA[b])[i] = hi;
            ((__hip_bfloat16*)pp.dstB[b])[i] = __float2bfloat16(r);
        }
    }
}

// ---------------- CSR build: bucket sort ----------------

__global__ __launch_bounds__(256) void bucket_count_kernel(
    const int* __restrict__ edge, const int* __restrict__ flags,
    int* __restrict__ bucket_cnt, int E, int n, int NB) {
    __shared__ int hist[1024];
    for (int i = threadIdx.x; i < NB; i += 256) hist[i] = 0;
    __syncthreads();
    int base = blockIdx.x * CHUNK;
    int end = base + CHUNK < E ? base + CHUNK : E;
    int is64 = flags[1];
    for (int e = base + (int)threadIdx.x; e < end; e += 256) {
        int r = is64 ? edge[2 * e] : edge[e];
        r = clampi(r, 0, n - 1);
        atomicAdd(&hist[r >> BSH], 1);
    }
    __syncthreads();
    for (int i = threadIdx.x; i < NB; i += 256) {
        int v = hist[i];
        if (v) atomicAdd(&bucket_cnt[i], v);
    }
}

__global__ __launch_bounds__(1024) void bucket_scan_kernel(
    const int* __restrict__ bucket_cnt, int* __restrict__ bucket_base,
    int* __restrict__ bucket_cursor, int* __restrict__ row_ptr, int NB, int n, int E) {
    __shared__ int sh[1024];
    int t = threadIdx.x;
    int v = (t < NB) ? bucket_cnt[t] : 0;
    sh[t] = v;
    __syncthreads();
    for (int off = 1; off < 1024; off <<= 1) {
        int u = (t >= off) ? sh[t - off] : 0;
        __syncthreads();
        sh[t] += u;
        __syncthreads();
    }
    if (t < NB) {
        int base = sh[t] - v;  // exclusive
        bucket_base[t] = base;
        bucket_cursor[t] = base;
    }
    if (t == 0) row_ptr[n] = E;
}

__global__ __launch_bounds__(256) void bucket_scatter_kernel(
    const int* __restrict__ edge, const int* __restrict__ flags,
    int* __restrict__ bucket_cursor, unsigned* __restrict__ packed,
    int E, int n, int NB) {
    __shared__ int hist[1024];
    __shared__ int cur[1024];
    int t = threadIdx.x;
    for (int i = t; i < NB; i += 256) hist[i] = 0;
    __syncthreads();
    int base = blockIdx.x * CHUNK;
    int end = base + CHUNK < E ? base + CHUNK : E;
    int is64 = flags[1];
    for (int e = base + t; e < end; e += 256) {
        int r = is64 ? edge[2 * e] : edge[e];
        r = clampi(r, 0, n - 1);
        atomicAdd(&hist[r >> BSH], 1);
    }
    __syncthreads();
    for (int i = t; i < NB; i += 256) {
        int h = hist[i];
        cur[i] = h ? atomicAdd(&bucket_cursor[i], h) : 0;
    }
    __syncthreads();
    for (int e = base + t; e < end; e += 256) {
        int r = is64 ? edge[2 * e] : edge[e];
        int c = is64 ? edge[2 * (E + e)] : edge[E + e];
        r = clampi(r, 0, n - 1);
        c = clampi(c, 0, n - 1);
        int p = atomicAdd(&cur[r >> BSH], 1);
        packed[p] = ((unsigned)(r & 127) << 17) | (unsigned)c;  // col < 2^17
    }
}

#define SORT_CAP 4096
__global__ __launch_bounds__(256) void bucket_sort_kernel(
    const unsigned* __restrict__ packed, const int* __restrict__ bucket_base,
    const int* __restrict__ bucket_cnt, int* __restrict__ row_ptr,
    int* __restrict__ col_sorted, int n) {
    __shared__ int hist[128], cur[128];
    __shared__ int out[SORT_CAP];
    int b = blockIdx.x;
    int s = bucket_base[b];
    int cnt = bucket_cnt[b];
    int t = threadIdx.x;
    if (t < 128) hist[t] = 0;
    __syncthreads();
    for (int i = t; i < cnt; i += 256) atomicAdd(&hist[packed[s + i] >> 17], 1);
    __syncthreads();
    int orig = (t < 128) ? hist[t] : 0;
    for (int off = 1; off < 128; off <<= 1) {
        int u = (t < 128 && t >= off) ? hist[t - off] : 0;
        __syncthreads();
        if (t < 128) hist[t] += u;
        __syncthreads();
    }
    if (t < 128) {
        int ex = hist[t] - orig;  // exclusive
        cur[t] = ex;
        int node = (b << BSH) + t;
        if (node < n) row_ptr[node] = s + ex;
    }
    __syncthreads();
    if (cnt <= SORT_CAP) {
        for (int i = t; i < cnt; i += 256) {
            unsigned pk = packed[s + i];
            int p = atomicAdd(&cur[pk >> 17], 1);
            out[p] = (int)(pk & 0x1FFFFu);
        }
        __syncthreads();
        for (int i = t; i < cnt; i += 256) col_sorted[s + i] = out[i];
    } else {  // overflow fallback
        for (int i = t; i < cnt; i += 256) {
            unsigned pk = packed[s + i];
            int p = atomicAdd(&cur[pk >> 17], 1);
            col_sorted[s + p] = (int)(pk & 0x1FFFFu);
        }
    }
}

// ---------------- Aggregation: batched pure-sum gather ----------------
// One node per wave; s,e wave-uniform. Inner loop loads 4 independent
// uint4 rows (4-deep MLP) then accumulates in packed f32x2.

__device__ __forceinline__ void accum_u4(uint4 u, f32x2* acc) {
    acc[0] += bfpair(u.x);
    acc[1] += bfpair(u.y);
    acc[2] += bfpair(u.z);
    acc[3] += bfpair(u.w);
}

template <int D>
__device__ __forceinline__ void gather_bf(const __hip_bfloat16* __restrict__ base,
                                          const int* __restrict__ cols,
                                          int s, int e, int sub, f32x2* acc) {
    constexpr int LPR = D / 8;
    constexpr int EPW = 64 / LPR;
    int cnt = e - s;
    int nfull = cnt / EPW;
    int rem = cnt - nfull * EPW;
    int k = s + sub;
    int it = 0;
    for (; it + 4 <= nfull; it += 4) {
        int c0 = cols[k];
        int c1 = cols[k + EPW];
        int c2 = cols[k + 2 * EPW];
        int c3 = cols[k + 3 * EPW];
        uint4 u0 = *reinterpret_cast<const uint4*>(base + (size_t)c0 * D);
        uint4 u1 = *reinterpret_cast<const uint4*>(base + (size_t)c1 * D);
        uint4 u2 = *reinterpret_cast<const uint4*>(base + (size_t)c2 * D);
        uint4 u3 = *reinterpret_cast<const uint4*>(base + (size_t)c3 * D);
        accum_u4(u0, acc);
        accum_u4(u1, acc);
        accum_u4(u2, acc);
        accum_u4(u3, acc);
        k += 4 * EPW;
    }
    if (it + 2 <= nfull) {
        int c0 = cols[k];
        int c1 = cols[k + EPW];
        uint4 u0 = *reinterpret_cast<const uint4*>(base + (size_t)c0 * D);
        uint4 u1 = *reinterpret_cast<const uint4*>(base + (size_t)c1 * D);
        accum_u4(u0, acc);
        accum_u4(u1, acc);
        k += 2 * EPW;
        it += 2;
    }
    if (it < nfull) {
        uint4 u = *reinterpret_cast<const uint4*>(base + (size_t)cols[k] * D);
        accum_u4(u, acc);
    }
    if (sub < rem) {
        uint4 u = *reinterpret_cast<const uint4*>(
            base + (size_t)cols[s + nfull * EPW + sub] * D);
        accum_u4(u, acc);
    }
}

template <int D>
__device__ __forceinline__ void gather_f32(const float* __restrict__ base,
                                           const int* __restrict__ cols,
                                           int s, int e, int sub, f32x2* acc) {
    constexpr int LPR = D / 8;
    constexpr int EPW = 64 / LPR;
    int cnt = e - s;
    int nfull = cnt / EPW;
    int rem = cnt - nfull * EPW;
    int k = s + sub;
    int it = 0;
    for (; it + 2 <= nfull; it += 2) {
        const float* p0 = base + (size_t)cols[k] * D;
        const float* p1 = base + (size_t)cols[k + EPW] * D;
        float4 a0 = *reinterpret_cast<const float4*>(p0);
        float4 b0 = *reinterpret_cast<const float4*>(p0 + 4);
        float4 a1 = *reinterpret_cast<const float4*>(p1);
        float4 b1 = *reinterpret_cast<const float4*>(p1 + 4);
        acc[0].x += a0.x; acc[0].y += a0.y; acc[1].x += a0.z; acc[1].y += a0.w;
        acc[2].x += b0.x; acc[2].y += b0.y; acc[3].x += b0.z; acc[3].y += b0.w;
        acc[0].x += a1.x; acc[0].y += a1.y; acc[1].x += a1.z; acc[1].y += a1.w;
        acc[2].x += b1.x; acc[2].y += b1.y; acc[3].x += b1.z; acc[3].y += b1.w;
        k += 2 * EPW;
    }
    if (it < nfull) {
        const float* p = base + (size_t)cols[k] * D;
        float4 a = *reinterpret_cast<const float4*>(p);
        float4 b = *reinterpret_cast<const float4*>(p + 4);
        acc[0].x += a.x; acc[0].y += a.y; acc[1].x += a.z; acc[1].y += a.w;
        acc[2].x += b.x; acc[2].y += b.y; acc[3].x += b.z; acc[3].y += b.w;
    }
    if (sub < rem) {
        const float* p = base + (size_t)cols[s + nfull * EPW + sub] * D;
        float4 a = *reinterpret_cast<const float4*>(p);
        float4 b = *reinterpret_cast<const float4*>(p + 4);
        acc[0].x += a.x; acc[0].y += a.y; acc[1].x += a.z; acc[1].y += a.w;
        acc[2].x += b.x; acc[2].y += b.y; acc[3].x += b.z; acc[3].y += b.w;
    }
}

template <int D, bool ADD_BIAS, bool OUT_FLAGDT>
__global__ __launch_bounds__(256) void agg_vec_kernel(
    const __hip_bfloat16* __restrict__ src, const int* __restrict__ row_ptr,
    const int* __restrict__ col_sorted, const float* __restrict__ bias,
    void* __restrict__ outp, const int* __restrict__ flags, int n) {
    constexpr int LPR = D / 8;
    int lane = threadIdx.x & 63;
    int node = blockIdx.x * 4 + (threadIdx.x >> 6);
    if (node >= n) return;
    int sub = lane / LPR;
    int c0 = (lane % LPR) * 8;

    int s = row_ptr[node];
    int e = row_ptr[node + 1];
    f32x2 acc[4];
#pragma unroll
    for (int j = 0; j < 4; ++j) acc[j] = (f32x2){0.f, 0.f};

    gather_bf<D>(src + c0, col_sorted, s, e, sub, acc);

#pragma unroll
    for (int j = 0; j < 4; ++j)
#pragma unroll
        for (int off = LPR; off < 64; off <<= 1) {
            acc[j].x += __shfl_xor(acc[j].x, off, 64);
            acc[j].y += __shfl_xor(acc[j].y, off, 64);
        }

    if (lane < LPR) {
        float recip = 1.0f / ((float)(e - s) + 1e-6f);
        float m[8];
#pragma unroll
        for (int j = 0; j < 4; ++j) {
            m[2 * j] = acc[j].x * recip;
            m[2 * j + 1] = acc[j].y * recip;
        }
        if (ADD_BIAS) {
#pragma unroll
            for (int j = 0; j < 8; ++j) m[j] += bias[c0 + j];
        }
        bool as_bf = !OUT_FLAGDT || flags[0];
        if (as_bf) {
            uint4 o;
            o.x = ((unsigned)f2bf(m[1]) << 16) | f2bf(m[0]);
            o.y = ((unsigned)f2bf(m[3]) << 16) | f2bf(m[2]);
            o.z = ((unsigned)f2bf(m[5]) << 16) | f2bf(m[4]);
            o.w = ((unsigned)f2bf(m[7]) << 16) | f2bf(m[6]);
            *reinterpret_cast<uint4*>((__hip_bfloat16*)outp + (size_t)node * D + c0) = o;
        } else {
            float* op = (float*)outp + (size_t)node * D + c0;
            *reinterpret_cast<float4*>(op) = make_float4(m[0], m[1], m[2], m[3]);
            *reinterpret_cast<float4*>(op + 4) = make_float4(m[4], m[5], m[6], m[7]);
        }
    }
}

// Layer-1 agg over raw x (dtype per flags), D=64, out bf16.
__global__ __launch_bounds__(256) void agg_x_kernel(
    const void* __restrict__ xsrc, const int* __restrict__ flags,
    const int* __restrict__ row_ptr, const int* __restrict__ col_sorted,
    __hip_bfloat16* __restrict__ out, int n) {
    constexpr int D = 64, LPR = 8;
    int lane = threadIdx.x & 63;
    int node = blockIdx.x * 4 + (threadIdx.x >> 6);
    if (node >= n) return;
    int sub = lane / LPR;
    int c0 = (lane % LPR) * 8;
    int s = row_ptr[node];
    int e = row_ptr[node + 1];
    f32x2 acc[4];
#pragma unroll
    for (int j = 0; j < 4; ++j) acc[j] = (f32x2){0.f, 0.f};

    if (flags[0])
        gather_bf<D>((const __hip_bfloat16*)xsrc + c0, col_sorted, s, e, sub, acc);
    else
        gather_f32<D>((const float*)xsrc + c0, col_sorted, s, e, sub, acc);

#pragma unroll
    for (int j = 0; j < 4; ++j)
#pragma unroll
        for (int off = LPR; off < 64; off <<= 1) {
            acc[j].x += __shfl_xor(acc[j].x, off, 64);
            acc[j].y += __shfl_xor(acc[j].y, off, 64);
        }

    if (lane < LPR) {
        float recip = 1.0f / ((float)(e - s) + 1e-6f);
        float m[8];
#pragma unroll
        for (int j = 0; j < 4; ++j) {
            m[2 * j] = acc[j].x * recip;
            m[2 * j + 1] = acc[j].y * recip;
        }
        uint4 o;
        o.x = ((unsigned)f2bf(m[1]) << 16) | f2bf(m[0]);
        o.y = ((unsigned)f2bf(m[3]) << 16) | f2bf(m[2]);
        o.z = ((unsigned)f2bf(m[5]) << 16) | f2bf(m[4]);
        o.w = ((unsigned)f2bf(m[7]) << 16) | f2bf(m[6]);
        *reinterpret_cast<uint4*>(out + (size_t)node * D + c0) = o;
    }
}

// ---------------- MFMA GEMM, LDS-staged W, optional fused BN stats ----------------

template <int D, int F, bool BIAS, bool APPLY_BN_A, bool STATS>
__global__ __launch_bounds__(256) void gemm_mfma_kernel(
    const __hip_bfloat16* __restrict__ A, const __hip_bfloat16* __restrict__ Whi,
    const __hip_bfloat16* __restrict__ Wlo, const float* __restrict__ bias,
    const float* __restrict__ bn_ss, float* __restrict__ stats,
    __hip_bfloat16* __restrict__ C, int n) {
    constexpr int JT = F / 16;
    constexpr int KCH = D / 32;
    constexpr int NF = KCH * JT * 2;
    __shared__ uint4 wlds[NF * 64];  // max 64 KB (D=128,F=128); reused for stats

    int t = threadIdx.x;
    for (int idx = t; idx < NF * 64; idx += 256) {
        int f = idx >> 6, ln = idx & 63;
        int kc = f / (JT * 2);
        int rem = f % (JT * 2);
        int jt = rem >> 1, h = rem & 1;
        int mm = ln & 15, qq = ln >> 4;
        const __hip_bfloat16* src =
            (h ? Wlo : Whi) + (size_t)(jt * 16 + mm) * D + kc * 32 + qq * 8;
        wlds[idx] = *reinterpret_cast<const uint4*>(src);
    }

    int lane = t & 63;
    int wave = t >> 6;
    int m = lane & 15;
    int quad = lane >> 4;
    int row_base = blockIdx.x * 128 + wave * 32;

    short8 af[2][KCH];
#pragma unroll
    for (int rs = 0; rs < 2; ++rs) {
        int r = row_base + rs * 16 + m;
        r = r < n ? r : n - 1;
        const __hip_bfloat16* ap = A + (size_t)r * D + quad * 8;
#pragma unroll
        for (int kc = 0; kc < KCH; ++kc) {
            union { uint4 u; short8 s; } tmp;
            tmp.u = *reinterpret_cast<const uint4*>(ap + kc * 32);
            af[rs][kc] = tmp.s;
        }
    }
    if (APPLY_BN_A) {
#pragma unroll
        for (int kc = 0; kc < KCH; ++kc) {
            int ch0 = kc * 32 + quad * 8;
            float sc[8], sh[8];
            *reinterpret_cast<float4*>(sc) = *reinterpret_cast<const float4*>(bn_ss + ch0);
            *reinterpret_cast<float4*>(sc + 4) = *reinterpret_cast<const float4*>(bn_ss + ch0 + 4);
            *reinterpret_cast<float4*>(sh) = *reinterpret_cast<const float4*>(bn_ss + 128 + ch0);
            *reinterpret_cast<float4*>(sh + 4) = *reinterpret_cast<const float4*>(bn_ss + 128 + ch0 + 4);
#pragma unroll
            for (int rs = 0; rs < 2; ++rs) {
#pragma unroll
                for (int j = 0; j < 8; ++j) {
                    float v = __uint_as_float(
                        ((unsigned)(unsigned short)af[rs][kc][j]) << 16);
                    v = fmaxf(fmaf(v, sc[j], sh[j]), 0.f);
                    af[rs][kc][j] = (short)f2bf(v);
                }
            }
        }
    }

    f32x4 acc[2][JT];
#pragma unroll
    for (int rs = 0; rs < 2; ++rs)
#pragma unroll
        for (int j = 0; j < JT; ++j) acc[rs][j] = {0.f, 0.f, 0.f, 0.f};

    __syncthreads();

#pragma unroll
    for (int kc = 0; kc < KCH; ++kc) {
#pragma unroll
        for (int jt = 0; jt < JT; ++jt) {
            int fb = (kc * JT + jt) * 2;
            union { uint4 u; short8 s; } bh, bl;
            bh.u = wlds[fb * 64 + lane];
            bl.u = wlds[(fb + 1) * 64 + lane];
            acc[0][jt] = __builtin_amdgcn_mfma_f32_16x16x32_bf16(af[0][kc], bh.s, acc[0][jt], 0, 0, 0);
            acc[1][jt] = __builtin_amdgcn_mfma_f32_16x16x32_bf16(af[1][kc], bh.s, acc[1][jt], 0, 0, 0);
            acc[0][jt] = __builtin_amdgcn_mfma_f32_16x16x32_bf16(af[0][kc], bl.s, acc[0][jt], 0, 0, 0);
            acc[1][jt] = __builtin_amdgcn_mfma_f32_16x16x32_bf16(af[1][kc], bl.s, acc[1][jt], 0, 0, 0);
        }
    }

#pragma unroll
    for (int rs = 0; rs < 2; ++rs) {
#pragma unroll
        for (int jt = 0; jt < JT; ++jt) {
            int col = jt * 16 + m;
            float bv = BIAS ? bias[col] : 0.f;
#pragma unroll
            for (int i = 0; i < 4; ++i) {
                int row = row_base + rs * 16 + quad * 4 + i;
                if (row < n)
                    C[(size_t)row * F + col] = __float2bfloat16(acc[rs][jt][i] + bv);
            }
        }
    }

    if (STATS) {
        float* slds = reinterpret_cast<float*>(wlds);  // 2*F floats
        __syncthreads();  // all waves done reading wlds
        for (int i = t; i < 2 * F; i += 256) slds[i] = 0.f;
        __syncthreads();
#pragma unroll
        for (int jt = 0; jt < JT; ++jt) {
            int col = jt * 16 + m;
            float bv = BIAS ? bias[col] : 0.f;
            float s = 0.f, q = 0.f;
#pragma unroll
            for (int rs = 0; rs < 2; ++rs) {
#pragma unroll
                for (int i = 0; i < 4; ++i) {
                    int row = row_base + rs * 16 + quad * 4 + i;
                    if (row < n) {
                        float v = acc[rs][jt][i] + bv;
                        s += v;
                        q += v * v;
                    }
                }
            }
            s += __shfl_xor(s, 16, 64); s += __shfl_xor(s, 32, 64);
            q += __shfl_xor(q, 16, 64); q += __shfl_xor(q, 32, 64);
            if (quad == 0) {
                atomicAdd(&slds[col], s);
                atomicAdd(&slds[F + col], q);
            }
        }
        __syncthreads();
        for (int i = t; i < 2 * F; i += 256) atomicAdd(&stats[i], slds[i]);
    }
}

// ---------------- BatchNorm ----------------

__global__ void bn_finalize_kernel(const float* __restrict__ sums,
                                   const float* __restrict__ gamma,
                                   const float* __restrict__ beta,
                                   float* __restrict__ ss, int n) {
    int c = threadIdx.x;  // 128
    float inv_n = 1.0f / (float)n;
    float mean = sums[c] * inv_n;
    float var = sums[128 + c] * inv_n - mean * mean;
    float inv = rsqrtf(var + 1e-5f);
    float scale = gamma[c] * inv;
    ss[c] = scale;
    ss[128 + c] = beta[c] - mean * scale;
}

// once-per-row BN apply + ReLU, in place on bf16 [n x 128]
__global__ __launch_bounds__(256) void bn_apply_kernel(__hip_bfloat16* __restrict__ X,
                                                       int ngroups,  // n*16
                                                       const float* __restrict__ ss) {
    __shared__ float lss[256];
    for (int i = threadIdx.x; i < 256; i += 256) lss[i] = ss[i];
    __syncthreads();
    int idx = blockIdx.x * 256 + threadIdx.x;
    int stride = gridDim.x * 256;
    for (; idx < ngroups; idx += stride) {
        int c0 = (idx & 15) * 8;
        uint4 u = *reinterpret_cast<uint4*>(X + (size_t)idx * 8);
        float v[8];
        v[0] = bf_lo(u.x); v[1] = bf_hi(u.x);
        v[2] = bf_lo(u.y); v[3] = bf_hi(u.y);
        v[4] = bf_lo(u.z); v[5] = bf_hi(u.z);
        v[6] = bf_lo(u.w); v[7] = bf_hi(u.w);
#pragma unroll
        for (int j = 0; j < 8; ++j) {
            float t = fmaf(v[j], lss[c0 + j], lss[128 + c0 + j]);
            v[j] = t > 0.f ? t : 0.f;
        }
        uint4 o;
        o.x = ((unsigned)f2bf(v[1]) << 16) | f2bf(v[0]);
        o.y = ((unsigned)f2bf(v[3]) << 16) | f2bf(v[2]);
        o.z = ((unsigned)f2bf(v[5]) << 16) | f2bf(v[4]);
        o.w = ((unsigned)f2bf(v[7]) << 16) | f2bf(v[6]);
        *reinterpret_cast<uint4*>(X + (size_t)idx * 8) = o;
    }
}

// ---------------- launch ----------------

extern "C" void kernel_launch(void* const* d_in, const int* in_sizes, int n_in,
                              void* d_out, int out_size, void* d_ws, size_t ws_size,
                              hipStream_t stream) {
    const void* x   = d_in[0];
    const int* edge = (const int*)d_in[1];

    int n = in_sizes[0] / 64;   // 100000
    int E = in_sizes[1] / 2;    // 1600000
    int NB = (n + 127) >> BSH;  // 782

    char* p = (char*)d_ws;
    auto carve = [&](size_t bytes) {
        char* q = p;
        p += (bytes + 255) & ~(size_t)255;
        return q;
    };
    int* flags      = (int*)carve(64);
    float* params   = (float*)carve(1024 * 4);
    __hip_bfloat16* Whi1 = (__hip_bfloat16*)carve(8192 * 2);
    __hip_bfloat16* Wlo1 = (__hip_bfloat16*)carve(8192 * 2);
    __hip_bfloat16* Whi2 = (__hip_bfloat16*)carve(16384 * 2);
    __hip_bfloat16* Wlo2 = (__hip_bfloat16*)carve(16384 * 2);
    __hip_bfloat16* Whi3 = (__hip_bfloat16*)carve(8192 * 2);
    __hip_bfloat16* Wlo3 = (__hip_bfloat16*)carve(8192 * 2);
    int* row_ptr    = (int*)carve((size_t)(n + 1) * 4);
    int* bucket_cnt = (int*)carve(1024 * 4);
    int* bucket_base= (int*)carve(1024 * 4);
    int* bucket_cur = (int*)carve(1024 * 4);
    float* bn_sums  = (float*)carve(512 * 4);   // [0:256) layer1, [256:512) layer2
    float* bn_ss1   = (float*)carve(256 * 4);
    float* bn_ss2   = (float*)carve(256 * 4);
    unsigned* packed= (unsigned*)carve((size_t)E * 4);
    int* col_sorted = (int*)carve((size_t)E * 4);
    __hip_bfloat16* bufA = (__hip_bfloat16*)carve((size_t)n * 128 * 2);
    __hip_bfloat16* bufB = (__hip_bfloat16*)carve((size_t)n * 128 * 2);
    carve(65536);  // slack

    float* b1f = params;        // 128
    float* g1f = b1f + 128;     // 128
    float* be1f = g1f + 128;    // 128
    float* b2f = be1f + 128;    // 128
    float* g2f = b2f + 128;     // 128
    float* be2f = g2f + 128;    // 128
    float* b3f = be2f + 128;    // 64

    detect_kernel<<<1, 1, 0, stream>>>((const unsigned int*)d_in[4], edge, flags);

    CvtPack pp;
    const int pidx[10] = {2, 3, 4, 5, 6, 7, 8, 9, 10, 11};
    void* pa[10] = {Whi1, b1f, g1f, be1f, Whi2, b2f, g2f, be2f, Whi3, b3f};
    void* pb[10] = {Wlo1, nullptr, nullptr, nullptr, Wlo2, nullptr, nullptr, nullptr, Wlo3, nullptr};
    const int psz[10] = {8192, 128, 128, 128, 16384, 128, 128, 128, 8192, 64};
    const int pmode[10] = {1, 0, 0, 0, 1, 0, 0, 0, 1, 0};
    for (int i = 0; i < 10; ++i) {
        pp.src[i] = d_in[pidx[i]];
        pp.dstA[i] = pa[i];
        pp.dstB[i] = pb[i];
        pp.sz[i] = psz[i];
        pp.mode[i] = pmode[i];
    }
    cvt_params_kernel<<<10, 256, 0, stream>>>(pp, flags);

    // CSR build via bucket sort (block-reservation scatter)
    hipMemsetAsync(bucket_cnt, 0, 1024 * 4, stream);
    hipMemsetAsync(bn_sums, 0, 512 * 4, stream);
    int nchunks = (E + CHUNK - 1) / CHUNK;
    bucket_count_kernel<<<nchunks, 256, 0, stream>>>(edge, flags, bucket_cnt, E, n, NB);
    bucket_scan_kernel<<<1, 1024, 0, stream>>>(bucket_cnt, bucket_base, bucket_cur, row_ptr, NB, n, E);
    bucket_scatter_kernel<<<nchunks, 256, 0, stream>>>(edge, flags, bucket_cur, packed, E, n, NB);
    bucket_sort_kernel<<<NB, 256, 0, stream>>>(packed, bucket_base, bucket_cnt, row_ptr, col_sorted, n);

    int gemm_grid = (n + 127) / 128;
    int agg_grid = (n + 3) / 4;

    // Layer 1: agg(x) -> bufA ; gemm (+fused BN1 stats) -> bufB ; finalize+apply
    agg_x_kernel<<<agg_grid, 256, 0, stream>>>(x, flags, row_ptr, col_sorted, bufA, n);
    gemm_mfma_kernel<64, 128, true, false, true><<<gemm_grid, 256, 0, stream>>>(
        bufA, Whi1, Wlo1, b1f, nullptr, bn_sums, bufB, n);
    bn_finalize_kernel<<<1, 128, 0, stream>>>(bn_sums, g1f, be1f, bn_ss1, n);
    bn_apply_kernel<<<1024, 256, 0, stream>>>(bufB, n * 16, bn_ss1);

    // Layer 2: agg -> bufA ; gemm (+fused BN2 stats) -> bufB ; finalize
    agg_vec_kernel<128, false, false><<<agg_grid, 256, 0, stream>>>(
        bufB, row_ptr, col_sorted, nullptr, bufA, flags, n);
    gemm_mfma_kernel<128, 128, true, false, true><<<gemm_grid, 256, 0, stream>>>(
        bufA, Whi2, Wlo2, b2f, nullptr, bn_sums + 256, bufB, n);
    bn_finalize_kernel<<<1, 128, 0, stream>>>(bn_sums + 256, g2f, be2f, bn_ss2, n);

    // Layer 3 (reordered): gemm with fused BN2+ReLU on A (no bias) -> bufA[N x 64];
    // agg D=64 + bias -> d_out
    gemm_mfma_kernel<128, 64, false, true, false><<<gemm_grid, 256, 0, stream>>>(
        bufB, Whi3, Wlo3, nullptr, bn_ss2, nullptr, bufA, n);
    agg_vec_kernel<64, true, true><<<agg_grid, 256, 0, stream>>>(
        bufA, row_ptr, col_sorted, b3f, d_out, flags, n);
}